// Round 2
// baseline (2892.372 us; speedup 1.0000x reference)
//
#include <hip/hip_runtime.h>
#include <hip/hip_bf16.h>

// Spiking attention, N=C=2048, T=10, heads=16, head_dim=128.
// Accuracy strategy: all discrete spike decisions made from fp64-accumulated
// GEMM results; everything between spikes and the final GEMM is exactly
// representable in fp32 (spikes in {-1,0,1}, attn = k/8, |sums| < 2^12).
//
//  K1 gemm_spike: fp64-acc GEMM [relu(x);relu(-x)](4096x2048) @ [wq|wk|wv](2048x6144),
//                 fp64 IF recurrence (T=10) in epilogue -> 10-bit spike masks (uint16).
//  K2 spike_attn: per token, rebuild {-1,0,1} spikes from masks, exact fp32
//                 attention, accumulate sum_t with transpose (d,h)->d*16+h.
//  K3 gemm_out:   fp64-acc GEMM xbar(2048x2048) @ wo(2048x2048) * 0.1 -> out.

#define TILE 128
#define BK 8

__global__ __launch_bounds__(256) void gemm_spike(
    const float* __restrict__ X, const float* __restrict__ W0,
    const float* __restrict__ W1, const float* __restrict__ W2,
    unsigned short* __restrict__ Mask) {
  __shared__ float As[BK][TILE];
  __shared__ float Bs[BK][TILE];
  const int tid = threadIdx.x;
  const int row0 = blockIdx.y * TILE, col0 = blockIdx.x * TILE;

  const int sel = col0 >> 11;  // 0:wq 1:wk 2:wv (2048-wide each)
  const float* W = (sel == 0) ? W0 : ((sel == 1) ? W1 : W2);
  const int jbase = col0 & 2047;

  const int am = tid >> 1;       // A row in tile
  const int ak = (tid & 1) * 4;  // A k offset
  const int bk = tid >> 5;       // B k row
  const int bj = (tid & 31) * 4; // B col offset
  const int tx = tid & 15, ty = tid >> 4;

  double acc[8][8];
#pragma unroll
  for (int i = 0; i < 8; i++)
#pragma unroll
    for (int j = 0; j < 8; j++) acc[i][j] = 0.0;

  for (int k0 = 0; k0 < 2048; k0 += BK) {
    const int gi = row0 + am;
    float4 av;
    if (gi < 2048) {
      av = *(const float4*)(X + (size_t)gi * 2048 + k0 + ak);
      av.x = fmaxf(av.x, 0.f); av.y = fmaxf(av.y, 0.f);
      av.z = fmaxf(av.z, 0.f); av.w = fmaxf(av.w, 0.f);
    } else {
      av = *(const float4*)(X + (size_t)(gi - 2048) * 2048 + k0 + ak);
      av.x = fmaxf(-av.x, 0.f); av.y = fmaxf(-av.y, 0.f);
      av.z = fmaxf(-av.z, 0.f); av.w = fmaxf(-av.w, 0.f);
    }
    As[ak + 0][am] = av.x;
    As[ak + 1][am] = av.y;
    As[ak + 2][am] = av.z;
    As[ak + 3][am] = av.w;

    const float4 bv = *(const float4*)(W + (size_t)(k0 + bk) * 2048 + jbase + bj);
    *(float4*)&Bs[bk][bj] = bv;
    __syncthreads();

#pragma unroll
    for (int kk = 0; kk < BK; kk++) {
      const float4 a0 = *(const float4*)&As[kk][ty * 4];
      const float4 a1 = *(const float4*)&As[kk][64 + ty * 4];
      const float4 b0 = *(const float4*)&Bs[kk][tx * 4];
      const float4 b1 = *(const float4*)&Bs[kk][64 + tx * 4];
      const double ar[8] = {(double)a0.x, (double)a0.y, (double)a0.z, (double)a0.w,
                            (double)a1.x, (double)a1.y, (double)a1.z, (double)a1.w};
      const double br[8] = {(double)b0.x, (double)b0.y, (double)b0.z, (double)b0.w,
                            (double)b1.x, (double)b1.y, (double)b1.z, (double)b1.w};
#pragma unroll
      for (int i = 0; i < 8; i++)
#pragma unroll
        for (int j = 0; j < 8; j++) acc[i][j] += ar[i] * br[j];
    }
    __syncthreads();
  }

  // Epilogue: fp64 IF recurrence (v += y; spike if v>=1; hard reset) -> bitmask
#pragma unroll
  for (int i = 0; i < 8; i++) {
    const int r = row0 + ((i < 4) ? (ty * 4 + i) : (64 + ty * 4 + (i - 4)));
#pragma unroll
    for (int j = 0; j < 8; j++) {
      const int c = col0 + ((j < 4) ? (tx * 4 + j) : (64 + tx * 4 + (j - 4)));
      const double y = acc[i][j];
      double v = 0.0;
      unsigned m = 0;
#pragma unroll
      for (int t = 0; t < 10; t++) {
        v += y;
        if (v >= 1.0) { m |= (1u << t); v = 0.0; }
      }
      Mask[(size_t)r * 6144 + c] = (unsigned short)m;
    }
  }
}

// One block per token. All arithmetic here is exact in fp32.
__global__ __launch_bounds__(256) void spike_attn(const unsigned short* __restrict__ Mask,
                                                  float* __restrict__ xbar) {
  const int n = blockIdx.x;
  const int tid = threadIdx.x;

  __shared__ float xqT[128 * 17];  // [d][h], pad 17 -> conflict-free
  __shared__ float xkT[128 * 17];
  __shared__ float xvT[128 * 17];
  __shared__ float attnS[16 * 17];

  const unsigned short* mp = Mask + (size_t)n * 6144;
  const unsigned short* mn = Mask + (size_t)(n + 2048) * 6144;

  unsigned q_p[8], q_n[8], k_p[8], k_n[8], v_p[8], v_n[8];
#pragma unroll
  for (int j = 0; j < 8; j++) {
    const int c = tid + 256 * j;
    q_p[j] = mp[c];        q_n[j] = mn[c];
    k_p[j] = mp[2048 + c]; k_n[j] = mn[2048 + c];
    v_p[j] = mp[4096 + c]; v_n[j] = mn[4096 + c];
  }

  float acc[8];
#pragma unroll
  for (int j = 0; j < 8; j++) acc[j] = 0.f;

  for (int t = 0; t < 10; t++) {
#pragma unroll
    for (int j = 0; j < 8; j++) {
      const int c = tid + 256 * j;
      const int d = c & 127, h = c >> 7;
      const int a = d * 17 + h;
      xqT[a] = (float)((q_p[j] >> t) & 1u) - (float)((q_n[j] >> t) & 1u);
      xkT[a] = (float)((k_p[j] >> t) & 1u) - (float)((k_n[j] >> t) & 1u);
      xvT[a] = (float)((v_p[j] >> t) & 1u) - (float)((v_n[j] >> t) & 1u);
    }
    __syncthreads();

    {  // attn[h][m] = 0.125 * sum_d xq[h,d]*xk[m,d] — exact (multiple of 1/8)
      const int h = tid >> 4, m = tid & 15;
      float a = 0.f;
#pragma unroll
      for (int d = 0; d < 128; d++) a += xqT[d * 17 + h] * xkT[d * 17 + m];
      attnS[h * 17 + m] = a * 0.125f;
    }
    __syncthreads();

    // xa accumulate at transposed position o = d*16 + h — exact
#pragma unroll
    for (int j = 0; j < 8; j++) {
      const int o = tid + 256 * j;
      const int h = o & 15, d = o >> 4;
      float s = 0.f;
#pragma unroll
      for (int m = 0; m < 16; m++) s += attnS[h * 17 + m] * xvT[d * 17 + m];
      acc[j] += s;
    }
    __syncthreads();
  }

#pragma unroll
  for (int j = 0; j < 8; j++) xbar[(size_t)n * 2048 + tid + 256 * j] = acc[j];
}

__global__ __launch_bounds__(256) void gemm_out(const float* __restrict__ A,
                                                const float* __restrict__ W,
                                                float* __restrict__ C) {
  __shared__ float As[BK][TILE];
  __shared__ float Bs[BK][TILE];
  const int tid = threadIdx.x;
  const int row0 = blockIdx.y * TILE, col0 = blockIdx.x * TILE;

  const int am = tid >> 1, ak = (tid & 1) * 4;
  const int bk = tid >> 5, bj = (tid & 31) * 4;
  const int tx = tid & 15, ty = tid >> 4;

  double acc[8][8];
#pragma unroll
  for (int i = 0; i < 8; i++)
#pragma unroll
    for (int j = 0; j < 8; j++) acc[i][j] = 0.0;

  for (int k0 = 0; k0 < 2048; k0 += BK) {
    const float4 av = *(const float4*)(A + (size_t)(row0 + am) * 2048 + k0 + ak);
    As[ak + 0][am] = av.x;
    As[ak + 1][am] = av.y;
    As[ak + 2][am] = av.z;
    As[ak + 3][am] = av.w;
    const float4 bv = *(const float4*)(W + (size_t)(k0 + bk) * 2048 + col0 + bj);
    *(float4*)&Bs[bk][bj] = bv;
    __syncthreads();

#pragma unroll
    for (int kk = 0; kk < BK; kk++) {
      const float4 a0 = *(const float4*)&As[kk][ty * 4];
      const float4 a1 = *(const float4*)&As[kk][64 + ty * 4];
      const float4 b0 = *(const float4*)&Bs[kk][tx * 4];
      const float4 b1 = *(const float4*)&Bs[kk][64 + tx * 4];
      const double ar[8] = {(double)a0.x, (double)a0.y, (double)a0.z, (double)a0.w,
                            (double)a1.x, (double)a1.y, (double)a1.z, (double)a1.w};
      const double br[8] = {(double)b0.x, (double)b0.y, (double)b0.z, (double)b0.w,
                            (double)b1.x, (double)b1.y, (double)b1.z, (double)b1.w};
#pragma unroll
      for (int i = 0; i < 8; i++)
#pragma unroll
        for (int j = 0; j < 8; j++) acc[i][j] += ar[i] * br[j];
    }
    __syncthreads();
  }

#pragma unroll
  for (int i = 0; i < 8; i++) {
    const int r = row0 + ((i < 4) ? (ty * 4 + i) : (64 + ty * 4 + (i - 4)));
    float4 v0, v1;
    v0.x = (float)(acc[i][0] * 0.1); v0.y = (float)(acc[i][1] * 0.1);
    v0.z = (float)(acc[i][2] * 0.1); v0.w = (float)(acc[i][3] * 0.1);
    v1.x = (float)(acc[i][4] * 0.1); v1.y = (float)(acc[i][5] * 0.1);
    v1.z = (float)(acc[i][6] * 0.1); v1.w = (float)(acc[i][7] * 0.1);
    *(float4*)(C + (size_t)r * 2048 + col0 + tx * 4) = v0;
    *(float4*)(C + (size_t)r * 2048 + col0 + 64 + tx * 4) = v1;
  }
}

extern "C" void kernel_launch(void* const* d_in, const int* in_sizes, int n_in,
                              void* d_out, int out_size, void* d_ws, size_t ws_size,
                              hipStream_t stream) {
  const float* x = (const float*)d_in[0];
  // d_in[1] = freqs_cis (unused)
  const float* wq = (const float*)d_in[2];
  const float* wk = (const float*)d_in[3];
  const float* wv = (const float*)d_in[4];
  const float* wo = (const float*)d_in[5];
  float* out = (float*)d_out;

  unsigned short* Mask = (unsigned short*)d_ws;                 // 4096*6144 u16 = 50.3 MB
  float* xbar = (float*)((char*)d_ws + (size_t)4096 * 6144 * 2);// 2048*2048 f32 = 16.8 MB

  gemm_spike<<<dim3(48, 32), 256, 0, stream>>>(x, wq, wk, wv, Mask);
  spike_attn<<<2048, 256, 0, stream>>>(Mask, xbar);
  gemm_out<<<dim3(16, 16), 256, 0, stream>>>(xbar, wo, out);
}

// Round 3
// 2069.850 us; speedup vs baseline: 1.3974x; 1.3974x over previous
//
#include <hip/hip_runtime.h>
#include <hip/hip_bf16.h>

// Spiking attention, N=C=2048, T=10, heads=16, head_dim=128.
//
// Accuracy strategy: spike decisions must match an exact (fp64) pipeline.
//  - K1 computes y = [relu(x);relu(-x)] @ [wq|wk|wv] in fp32 (fast), runs the
//    IF recurrence in fp64 on the fp32 y, and CERTIFIES each channel: if the
//    trajectory never comes within FLAG_EPS=2e-4 of threshold, the decision
//    sequence is provably identical to exact-y (|dy| <= ~4e-6 stat. max,
//    amplification <= 10x, margin 5x). Otherwise flag -> rescue list.
//  - rescue recomputes flagged channels (~0.1%) with an fp64 dot against a
//    pre-transposed W^T (coalesced), overwriting the mask. Result: masks are
//    bit-identical to the all-fp64 R2 kernel.
//  - K2 (spike attention) is exact in fp32; K3 accumulates in fp64.
//
// ws layout (<= 109.1 MB, R1 proved >= 117.4 MB available):
//   [Mask u16 4096x6144 : 50.33 MB][WT f32 6144x2048 : 50.33 MB (aliased by
//    xbar f32 2048x2048 after rescue)][list u32 2M : 8 MB][counter u32]

#define TILE 128
#define BK 8
#define LIST_CAP (2u * 1024u * 1024u)
#define FLAG_EPS 2e-4

// ---- K0: transpose W (3x 2048x2048 col-major cols -> WT rows), zero counter
__global__ __launch_bounds__(256) void transpose_w(
    const float* __restrict__ W0, const float* __restrict__ W1,
    const float* __restrict__ W2, float* __restrict__ WT,
    unsigned* __restrict__ cnt) {
  if (blockIdx.x == 0 && blockIdx.y == 0 && threadIdx.x == 0 && threadIdx.y == 0)
    *cnt = 0u;
  __shared__ float tile[32][33];
  const int k0 = blockIdx.x * 32;        // 0..2047
  const int c0 = blockIdx.y * 32;        // 0..6143
  const int sel = c0 >> 11;
  const float* W = (sel == 0) ? W0 : ((sel == 1) ? W1 : W2);
  const int cc0 = c0 & 2047;
  const int tx = threadIdx.x, ty = threadIdx.y;  // (32,8)
#pragma unroll
  for (int rep = 0; rep < 4; rep++)
    tile[ty + 8 * rep][tx] = W[(size_t)(k0 + ty + 8 * rep) * 2048 + cc0 + tx];
  __syncthreads();
#pragma unroll
  for (int rep = 0; rep < 4; rep++)
    WT[(size_t)(c0 + ty + 8 * rep) * 2048 + k0 + tx] = tile[tx][ty + 8 * rep];
}

// ---- K1: fp32 GEMM + fp64 IF recurrence + certification flags
__global__ __launch_bounds__(256) void gemm_spike(
    const float* __restrict__ X, const float* __restrict__ W0,
    const float* __restrict__ W1, const float* __restrict__ W2,
    unsigned short* __restrict__ Mask, unsigned* __restrict__ list,
    unsigned* __restrict__ cnt) {
  __shared__ float As[BK][TILE];
  __shared__ float Bs[BK][TILE];
  const int tid = threadIdx.x;
  const int row0 = blockIdx.y * TILE, col0 = blockIdx.x * TILE;

  const int sel = col0 >> 11;  // 0:wq 1:wk 2:wv
  const float* W = (sel == 0) ? W0 : ((sel == 1) ? W1 : W2);
  const int jbase = col0 & 2047;

  const int am = tid >> 1;       // A row in tile
  const int ak = (tid & 1) * 4;  // A k offset
  const int bk = tid >> 5;       // B k row
  const int bj = (tid & 31) * 4; // B col offset
  const int tx = tid & 15, ty = tid >> 4;

  float acc[8][8];
#pragma unroll
  for (int i = 0; i < 8; i++)
#pragma unroll
    for (int j = 0; j < 8; j++) acc[i][j] = 0.f;

  for (int k0 = 0; k0 < 2048; k0 += BK) {
    const int gi = row0 + am;
    float4 av;
    if (gi < 2048) {
      av = *(const float4*)(X + (size_t)gi * 2048 + k0 + ak);
      av.x = fmaxf(av.x, 0.f); av.y = fmaxf(av.y, 0.f);
      av.z = fmaxf(av.z, 0.f); av.w = fmaxf(av.w, 0.f);
    } else {
      av = *(const float4*)(X + (size_t)(gi - 2048) * 2048 + k0 + ak);
      av.x = fmaxf(-av.x, 0.f); av.y = fmaxf(-av.y, 0.f);
      av.z = fmaxf(-av.z, 0.f); av.w = fmaxf(-av.w, 0.f);
    }
    As[ak + 0][am] = av.x;
    As[ak + 1][am] = av.y;
    As[ak + 2][am] = av.z;
    As[ak + 3][am] = av.w;

    const float4 bv = *(const float4*)(W + (size_t)(k0 + bk) * 2048 + jbase + bj);
    *(float4*)&Bs[bk][bj] = bv;
    __syncthreads();

#pragma unroll
    for (int kk = 0; kk < BK; kk++) {
      const float4 a0 = *(const float4*)&As[kk][ty * 4];
      const float4 a1 = *(const float4*)&As[kk][64 + ty * 4];
      const float4 b0 = *(const float4*)&Bs[kk][tx * 4];
      const float4 b1 = *(const float4*)&Bs[kk][64 + tx * 4];
      const float ar[8] = {a0.x, a0.y, a0.z, a0.w, a1.x, a1.y, a1.z, a1.w};
      const float br[8] = {b0.x, b0.y, b0.z, b0.w, b1.x, b1.y, b1.z, b1.w};
#pragma unroll
      for (int i = 0; i < 8; i++)
#pragma unroll
        for (int j = 0; j < 8; j++) acc[i][j] += ar[i] * br[j];
    }
    __syncthreads();
  }

  // Epilogue: fp64 IF recurrence on fp32 y; certify or flag.
#pragma unroll
  for (int i = 0; i < 8; i++) {
    const int r = row0 + ((i < 4) ? (ty * 4 + i) : (64 + ty * 4 + (i - 4)));
#pragma unroll
    for (int j = 0; j < 8; j++) {
      const int c = col0 + ((j < 4) ? (tx * 4 + j) : (64 + tx * 4 + (j - 4)));
      const double y = (double)acc[i][j];
      double v = 0.0, mind = 1e9;
      unsigned m = 0;
#pragma unroll
      for (int t = 0; t < 10; t++) {
        v += y;
        const double d = v - 1.0;
        mind = fmin(mind, fabs(d));
        if (d >= 0.0) { m |= (1u << t); v = 0.0; }
      }
      Mask[(size_t)r * 6144 + c] = (unsigned short)m;
      if (mind < FLAG_EPS) {
        const unsigned idx = atomicAdd(cnt, 1u);
        if (idx < LIST_CAP) list[idx] = ((unsigned)r << 13) | (unsigned)c;
      }
    }
  }
}

// ---- K2: fp64 rescue of flagged channels (one wave per item)
__global__ __launch_bounds__(256) void rescue(
    const float* __restrict__ X, const float* __restrict__ WT,
    const unsigned* __restrict__ list, const unsigned* __restrict__ cnt,
    unsigned short* __restrict__ Mask) {
  const unsigned nItems = min(*cnt, LIST_CAP);
  const unsigned gtid = blockIdx.x * blockDim.x + threadIdx.x;
  const unsigned wave = gtid >> 6, lane = gtid & 63;
  const unsigned nWaves = (gridDim.x * blockDim.x) >> 6;

  for (unsigned i = wave; i < nItems; i += nWaves) {
    const unsigned e = list[i];
    const int r = (int)(e >> 13), c = (int)(e & 8191u);
    const float* xrow = X + (size_t)((r < 2048) ? r : r - 2048) * 2048;
    const float sgn = (r < 2048) ? 1.f : -1.f;
    const float* wrow = WT + (size_t)c * 2048;
    double s = 0.0;
#pragma unroll
    for (int it = 0; it < 8; it++) {
      const int k = (it * 64 + (int)lane) * 4;
      const float4 xv = *(const float4*)(xrow + k);
      const float4 wv = *(const float4*)(wrow + k);
      const float a0 = fmaxf(sgn * xv.x, 0.f);
      const float a1 = fmaxf(sgn * xv.y, 0.f);
      const float a2 = fmaxf(sgn * xv.z, 0.f);
      const float a3 = fmaxf(sgn * xv.w, 0.f);
      s += (double)a0 * (double)wv.x + (double)a1 * (double)wv.y +
           (double)a2 * (double)wv.z + (double)a3 * (double)wv.w;
    }
#pragma unroll
    for (int off = 32; off > 0; off >>= 1) s += __shfl_down(s, off);
    if (lane == 0) {
      double v = 0.0;
      unsigned m = 0;
#pragma unroll
      for (int t = 0; t < 10; t++) {
        v += s;
        if (v >= 1.0) { m |= (1u << t); v = 0.0; }
      }
      Mask[(size_t)r * 6144 + c] = (unsigned short)m;
    }
  }
}

// ---- K3: per-token spike attention (exact fp32), transpose (d,h)->d*16+h
__global__ __launch_bounds__(256) void spike_attn(const unsigned short* __restrict__ Mask,
                                                  float* __restrict__ xbar) {
  const int n = blockIdx.x;
  const int tid = threadIdx.x;

  __shared__ float xqT[128 * 17];  // [d][h], pad 17 -> conflict-free
  __shared__ float xkT[128 * 17];
  __shared__ float xvT[128 * 17];
  __shared__ float attnS[16 * 17];

  const unsigned short* mp = Mask + (size_t)n * 6144;
  const unsigned short* mn = Mask + (size_t)(n + 2048) * 6144;

  unsigned q_p[8], q_n[8], k_p[8], k_n[8], v_p[8], v_n[8];
#pragma unroll
  for (int j = 0; j < 8; j++) {
    const int c = tid + 256 * j;
    q_p[j] = mp[c];        q_n[j] = mn[c];
    k_p[j] = mp[2048 + c]; k_n[j] = mn[2048 + c];
    v_p[j] = mp[4096 + c]; v_n[j] = mn[4096 + c];
  }

  float acc[8];
#pragma unroll
  for (int j = 0; j < 8; j++) acc[j] = 0.f;

  for (int t = 0; t < 10; t++) {
#pragma unroll
    for (int j = 0; j < 8; j++) {
      const int c = tid + 256 * j;
      const int d = c & 127, h = c >> 7;
      const int a = d * 17 + h;
      xqT[a] = (float)((q_p[j] >> t) & 1u) - (float)((q_n[j] >> t) & 1u);
      xkT[a] = (float)((k_p[j] >> t) & 1u) - (float)((k_n[j] >> t) & 1u);
      xvT[a] = (float)((v_p[j] >> t) & 1u) - (float)((v_n[j] >> t) & 1u);
    }
    __syncthreads();

    {  // attn[h][m] = 0.125 * sum_d xq[h,d]*xk[m,d] — exact multiple of 1/8
      const int h = tid >> 4, m = tid & 15;
      float a = 0.f;
#pragma unroll
      for (int d = 0; d < 128; d++) a += xqT[d * 17 + h] * xkT[d * 17 + m];
      attnS[h * 17 + m] = a * 0.125f;
    }
    __syncthreads();

#pragma unroll
    for (int j = 0; j < 8; j++) {
      const int o = tid + 256 * j;
      const int h = o & 15, d = o >> 4;
      float s = 0.f;
#pragma unroll
      for (int m = 0; m < 16; m++) s += attnS[h * 17 + m] * xvT[d * 17 + m];
      acc[j] += s;
    }
    __syncthreads();
  }

#pragma unroll
  for (int j = 0; j < 8; j++) xbar[(size_t)n * 2048 + tid + 256 * j] = acc[j];
}

// ---- K4: out = (xbar @ wo) * 0.1, fp64 accumulation
__global__ __launch_bounds__(256) void gemm_out(const float* __restrict__ A,
                                                const float* __restrict__ W,
                                                float* __restrict__ C) {
  __shared__ float As[BK][TILE];
  __shared__ float Bs[BK][TILE];
  const int tid = threadIdx.x;
  const int row0 = blockIdx.y * TILE, col0 = blockIdx.x * TILE;

  const int am = tid >> 1, ak = (tid & 1) * 4;
  const int bk = tid >> 5, bj = (tid & 31) * 4;
  const int tx = tid & 15, ty = tid >> 4;

  double acc[8][8];
#pragma unroll
  for (int i = 0; i < 8; i++)
#pragma unroll
    for (int j = 0; j < 8; j++) acc[i][j] = 0.0;

  for (int k0 = 0; k0 < 2048; k0 += BK) {
    const float4 av = *(const float4*)(A + (size_t)(row0 + am) * 2048 + k0 + ak);
    As[ak + 0][am] = av.x;
    As[ak + 1][am] = av.y;
    As[ak + 2][am] = av.z;
    As[ak + 3][am] = av.w;
    const float4 bv = *(const float4*)(W + (size_t)(k0 + bk) * 2048 + col0 + bj);
    *(float4*)&Bs[bk][bj] = bv;
    __syncthreads();

#pragma unroll
    for (int kk = 0; kk < BK; kk++) {
      const float4 a0 = *(const float4*)&As[kk][ty * 4];
      const float4 a1 = *(const float4*)&As[kk][64 + ty * 4];
      const float4 b0 = *(const float4*)&Bs[kk][tx * 4];
      const float4 b1 = *(const float4*)&Bs[kk][64 + tx * 4];
      const double ar[8] = {(double)a0.x, (double)a0.y, (double)a0.z, (double)a0.w,
                            (double)a1.x, (double)a1.y, (double)a1.z, (double)a1.w};
      const double br[8] = {(double)b0.x, (double)b0.y, (double)b0.z, (double)b0.w,
                            (double)b1.x, (double)b1.y, (double)b1.z, (double)b1.w};
#pragma unroll
      for (int i = 0; i < 8; i++)
#pragma unroll
        for (int j = 0; j < 8; j++) acc[i][j] += ar[i] * br[j];
    }
    __syncthreads();
  }

#pragma unroll
  for (int i = 0; i < 8; i++) {
    const int r = row0 + ((i < 4) ? (ty * 4 + i) : (64 + ty * 4 + (i - 4)));
    float4 v0, v1;
    v0.x = (float)(acc[i][0] * 0.1); v0.y = (float)(acc[i][1] * 0.1);
    v0.z = (float)(acc[i][2] * 0.1); v0.w = (float)(acc[i][3] * 0.1);
    v1.x = (float)(acc[i][4] * 0.1); v1.y = (float)(acc[i][5] * 0.1);
    v1.z = (float)(acc[i][6] * 0.1); v1.w = (float)(acc[i][7] * 0.1);
    *(float4*)(C + (size_t)r * 2048 + col0 + tx * 4) = v0;
    *(float4*)(C + (size_t)r * 2048 + col0 + 64 + tx * 4) = v1;
  }
}

extern "C" void kernel_launch(void* const* d_in, const int* in_sizes, int n_in,
                              void* d_out, int out_size, void* d_ws, size_t ws_size,
                              hipStream_t stream) {
  const float* x = (const float*)d_in[0];
  // d_in[1] = freqs_cis (unused)
  const float* wq = (const float*)d_in[2];
  const float* wk = (const float*)d_in[3];
  const float* wv = (const float*)d_in[4];
  const float* wo = (const float*)d_in[5];
  float* out = (float*)d_out;

  char* ws = (char*)d_ws;
  unsigned short* Mask = (unsigned short*)ws;                       // 50.33 MB
  float* WT   = (float*)(ws + (size_t)4096 * 6144 * 2);             // 50.33 MB
  float* xbar = WT;                                                 // aliases WT (WT dead after rescue)
  unsigned* list = (unsigned*)(ws + (size_t)4096 * 6144 * 2 + (size_t)6144 * 2048 * 4);  // 8 MB
  unsigned* cnt  = list + LIST_CAP;

  transpose_w<<<dim3(64, 192), dim3(32, 8), 0, stream>>>(wq, wk, wv, WT, cnt);
  gemm_spike<<<dim3(48, 32), 256, 0, stream>>>(x, wq, wk, wv, Mask, list, cnt);
  rescue<<<256, 256, 0, stream>>>(x, WT, list, cnt, Mask);
  spike_attn<<<2048, 256, 0, stream>>>(Mask, xbar);
  gemm_out<<<dim3(16, 16), 256, 0, stream>>>(xbar, wo, out);
}

// Round 4
// 1756.543 us; speedup vs baseline: 1.6466x; 1.1784x over previous
//
#include <hip/hip_runtime.h>
#include <hip/hip_bf16.h>

// Spiking attention, N=C=2048, T=10, heads=16, head_dim=128.
//
//  K0 transpose_w: WTf32[c][k] (coalesced rescue + B-staging source), zero cnt.
//  K1 gemm_spike:  y = [relu(x);relu(-x)] @ [wq|wk|wv] via bf16x3-split MFMA
//                  (6 passes, exact to fp32-GEMM error class), closed-form IF
//                  recurrence -> 10-bit spike mask, certify (FLAG_EPS) or flag.
//  K2 rescue:      fp64 dot for flagged channels -> masks bit-identical to the
//                  all-fp64 pipeline.
//  K3 spike_attn:  exact fp32 attention over spikes, transpose (d,h)->d*16+h.
//  K4 gemm_out:    out = (xbar @ wo) * 0.1, fp32 acc (error ~1e-5 << slack).
//
// ws layout (108.66 MB, proven available in R2/R3):
//   [Mask u16 4096x6144 : 50.33 MB][WTf32 6144x2048 : 50.33 MB (xbar aliases
//    after rescue)][list u32 2M : 8 MB][cnt u32]

#define LIST_CAP (2u * 1024u * 1024u)
#define FLAG_EPS 2e-4f

typedef __attribute__((ext_vector_type(8))) short short8;
typedef __attribute__((ext_vector_type(4))) float floatx4;

// ---- K0: transpose W (3x 2048x2048 -> WT rows), zero counter
__global__ __launch_bounds__(256) void transpose_w(
    const float* __restrict__ W0, const float* __restrict__ W1,
    const float* __restrict__ W2, float* __restrict__ WT,
    unsigned* __restrict__ cnt) {
  if (blockIdx.x == 0 && blockIdx.y == 0 && threadIdx.x == 0 && threadIdx.y == 0)
    *cnt = 0u;
  __shared__ float tile[32][33];
  const int k0 = blockIdx.x * 32;  // 0..2047
  const int c0 = blockIdx.y * 32;  // 0..6143
  const int sel = c0 >> 11;
  const float* W = (sel == 0) ? W0 : ((sel == 1) ? W1 : W2);
  const int cc0 = c0 & 2047;
  const int tx = threadIdx.x, ty = threadIdx.y;  // (32,8)
#pragma unroll
  for (int rep = 0; rep < 4; rep++)
    tile[ty + 8 * rep][tx] = W[(size_t)(k0 + ty + 8 * rep) * 2048 + cc0 + tx];
  __syncthreads();
#pragma unroll
  for (int rep = 0; rep < 4; rep++)
    WT[(size_t)(c0 + ty + 8 * rep) * 2048 + k0 + tx] = tile[tx][ty + 8 * rep];
}

// Pack two fp32 -> one u32 holding 2 bf16 (lo elem in low half).
__device__ __forceinline__ unsigned pack_hi(unsigned u0, unsigned u1) {
  return (u0 >> 16) | (u1 & 0xFFFF0000u);
}

// ---- K1: bf16x3-split MFMA GEMM + closed-form IF + certification flags
// Block tile 128(m) x 192(n), BK=32, 256 threads = 2x2 waves, wave tile 64x96.
#define STRIDE 40  // shorts per 32-k row (80 B: 16B-aligned b128, <=2-way banks)
__global__ __launch_bounds__(256) void gemm_spike(
    const float* __restrict__ X, const float* __restrict__ WT,
    unsigned short* __restrict__ Mask, unsigned* __restrict__ list,
    unsigned* __restrict__ cnt) {
  __shared__ short As[3][128 * STRIDE];
  __shared__ short Bs[3][192 * STRIDE];
  __shared__ unsigned lutS[16];

  const int tid = threadIdx.x;
  const int row0 = blockIdx.y * 128;   // 0..4095 (by<16: pos branch)
  const int col0 = blockIdx.x * 192;   // 0..6143 (WT rows, no matrix straddle)

  if (tid < 16) {
    const unsigned lut[16] = {0u, 0x3FFu, 0x2AAu, 0x124u, 0x88u, 0x210u,
                              0x20u, 0x40u, 0x80u, 0x100u, 0x200u,
                              0u, 0u, 0u, 0u, 0u};
    lutS[tid] = lut[tid];
  }

  const int lane = tid & 63;
  const int wave = tid >> 6;
  const int wr = wave >> 1, wc = wave & 1;  // wave grid 2x2
  const int lm = lane & 15, lg = lane >> 4; // frag row / k-group

  const float sgn = (blockIdx.y < 16) ? 1.f : -1.f;
  const float* Xb = X + (size_t)((blockIdx.y < 16) ? row0 : row0 - 2048) * 2048;

  floatx4 acc[4][6];
#pragma unroll
  for (int i = 0; i < 4; i++)
#pragma unroll
    for (int j = 0; j < 6; j++) acc[i][j] = (floatx4){0.f, 0.f, 0.f, 0.f};

  for (int k0 = 0; k0 < 2048; k0 += 32) {
    // ---- global loads: combined rows 0..127 = A, 128..319 = B(WT)
    float4 v[10];
#pragma unroll
    for (int s = 0; s < 10; s++) {
      const int q = tid + 256 * s;      // 0..2559
      const int gr = q >> 3;            // combined row
      const int kk = (q & 7) * 4;       // k within tile
      if (gr < 128) {
        float4 a = *(const float4*)(Xb + (size_t)gr * 2048 + k0 + kk);
        a.x = fmaxf(sgn * a.x, 0.f); a.y = fmaxf(sgn * a.y, 0.f);
        a.z = fmaxf(sgn * a.z, 0.f); a.w = fmaxf(sgn * a.w, 0.f);
        v[s] = a;
      } else {
        v[s] = *(const float4*)(WT + (size_t)(col0 + gr - 128) * 2048 + k0 + kk);
      }
    }
    __syncthreads();  // previous iteration's fragment reads complete

    // ---- convert to 3 bf16 planes, write to LDS
#pragma unroll
    for (int s = 0; s < 10; s++) {
      const int q = tid + 256 * s;
      const int gr = q >> 3;
      const int kk = (q & 7) * 4;
      const float e[4] = {v[s].x, v[s].y, v[s].z, v[s].w};
      unsigned u1[4], u2[4], u3[4];
#pragma unroll
      for (int m = 0; m < 4; m++) {
        const unsigned u = __float_as_uint(e[m]);
        u1[m] = u & 0xFFFF0000u;
        const float r1 = e[m] - __uint_as_float(u1[m]);
        const unsigned w2 = __float_as_uint(r1) & 0xFFFF0000u;
        u2[m] = w2;
        const float r2 = r1 - __uint_as_float(w2);
        u3[m] = __float_as_uint(r2) + 0x8000u;  // RNE-ish on last split
      }
      uint2 p1, p2, p3;
      p1.x = pack_hi(u1[0], u1[1]); p1.y = pack_hi(u1[2], u1[3]);
      p2.x = pack_hi(u2[0], u2[1]); p2.y = pack_hi(u2[2], u2[3]);
      p3.x = pack_hi(u3[0], u3[1]); p3.y = pack_hi(u3[2], u3[3]);
      short* base;
      int idx;
      if (gr < 128) { base = &As[0][0]; idx = gr * STRIDE + kk; }
      else          { base = &Bs[0][0]; idx = (gr - 128) * STRIDE + kk; }
      *(uint2*)(base + idx) = p1;
      *(uint2*)(base + 128 * 0 + ((gr < 128) ? 128 : 192) * STRIDE * 1 + idx) = p2;
      *(uint2*)(base + ((gr < 128) ? 128 : 192) * STRIDE * 2 + idx) = p3;
    }
    __syncthreads();

    // ---- fragment loads + 6 MFMA passes (a1,b1 persistent)
    const int aoff = (64 * wr + lm) * STRIDE + 8 * lg;
    const int boff = (96 * wc + lm) * STRIDE + 8 * lg;
    short8 a1[4], b1[6];
#pragma unroll
    for (int i = 0; i < 4; i++) a1[i] = *(const short8*)&As[0][aoff + 16 * i * STRIDE];
#pragma unroll
    for (int j = 0; j < 6; j++) b1[j] = *(const short8*)&Bs[0][boff + 16 * j * STRIDE];
#pragma unroll
    for (int i = 0; i < 4; i++)
#pragma unroll
      for (int j = 0; j < 6; j++)
        acc[i][j] = __builtin_amdgcn_mfma_f32_16x16x32_bf16(a1[i], b1[j], acc[i][j], 0, 0, 0);

    {
      short8 b2[6];
#pragma unroll
      for (int j = 0; j < 6; j++) b2[j] = *(const short8*)&Bs[1][boff + 16 * j * STRIDE];
#pragma unroll
      for (int i = 0; i < 4; i++)
#pragma unroll
        for (int j = 0; j < 6; j++)
          acc[i][j] = __builtin_amdgcn_mfma_f32_16x16x32_bf16(a1[i], b2[j], acc[i][j], 0, 0, 0);
      short8 a2[4];
#pragma unroll
      for (int i = 0; i < 4; i++) a2[i] = *(const short8*)&As[1][aoff + 16 * i * STRIDE];
#pragma unroll
      for (int i = 0; i < 4; i++)
#pragma unroll
        for (int j = 0; j < 6; j++)
          acc[i][j] = __builtin_amdgcn_mfma_f32_16x16x32_bf16(a2[i], b1[j], acc[i][j], 0, 0, 0);
#pragma unroll
      for (int i = 0; i < 4; i++)
#pragma unroll
        for (int j = 0; j < 6; j++)
          acc[i][j] = __builtin_amdgcn_mfma_f32_16x16x32_bf16(a2[i], b2[j], acc[i][j], 0, 0, 0);
    }
    {
      short8 b3[6];
#pragma unroll
      for (int j = 0; j < 6; j++) b3[j] = *(const short8*)&Bs[2][boff + 16 * j * STRIDE];
#pragma unroll
      for (int i = 0; i < 4; i++)
#pragma unroll
        for (int j = 0; j < 6; j++)
          acc[i][j] = __builtin_amdgcn_mfma_f32_16x16x32_bf16(a1[i], b3[j], acc[i][j], 0, 0, 0);
      short8 a3[4];
#pragma unroll
      for (int i = 0; i < 4; i++) a3[i] = *(const short8*)&As[2][aoff + 16 * i * STRIDE];
#pragma unroll
      for (int i = 0; i < 4; i++)
#pragma unroll
        for (int j = 0; j < 6; j++)
          acc[i][j] = __builtin_amdgcn_mfma_f32_16x16x32_bf16(a3[i], b1[j], acc[i][j], 0, 0, 0);
    }
  }

  // ---- epilogue: closed-form IF recurrence on y, certify or flag
  // C/D layout (m89): col = lane&15, row = (lane>>4)*4 + reg.
#pragma unroll
  for (int i = 0; i < 4; i++) {
#pragma unroll
    for (int j = 0; j < 6; j++) {
      const int gn = col0 + 96 * wc + 16 * j + lm;
#pragma unroll
      for (int vv = 0; vv < 4; vv++) {
        const int gm = row0 + 64 * wr + 16 * i + 4 * lg + vv;
        const float y = acc[i][j][vv];
        float r = __builtin_amdgcn_rcpf(y);
        r = fminf(fmaxf(r, -1.0f), 12.0f);
        const float jf = floorf(r);
        const float d0 = fmaf(jf, y, -1.0f);  // exact sign of jf*y - 1
        const float i0 = fminf(fmaxf(jf, 1.0f), 10.0f);
        const float i1 = fminf(fmaxf(jf + 1.0f, 1.0f), 10.0f);
        const float e0 = fmaf(i0, y, -1.0f);
        const float e1 = fmaf(i1, y, -1.0f);
        const float mind = fminf(fabsf(e0), fabsf(e1));
        const float Jf = (d0 >= 0.0f) ? jf : jf + 1.0f;
        const int J = (int)Jf;  // -1..13
        const unsigned mask = (J <= 10) ? lutS[J & 15] : 0u;
        Mask[(size_t)gm * 6144 + gn] = (unsigned short)mask;
        if (mind < FLAG_EPS) {
          const unsigned idx = atomicAdd(cnt, 1u);
          if (idx < LIST_CAP) list[idx] = ((unsigned)gm << 13) | (unsigned)gn;
        }
      }
    }
  }
}

// ---- K2: fp64 rescue of flagged channels (one wave per item)
__global__ __launch_bounds__(256) void rescue(
    const float* __restrict__ X, const float* __restrict__ WT,
    const unsigned* __restrict__ list, const unsigned* __restrict__ cnt,
    unsigned short* __restrict__ Mask) {
  const unsigned nItems = min(*cnt, LIST_CAP);
  const unsigned gtid = blockIdx.x * blockDim.x + threadIdx.x;
  const unsigned wave = gtid >> 6, lane = gtid & 63;
  const unsigned nWaves = (gridDim.x * blockDim.x) >> 6;

  for (unsigned i = wave; i < nItems; i += nWaves) {
    const unsigned e = list[i];
    const int r = (int)(e >> 13), c = (int)(e & 8191u);
    const float* xrow = X + (size_t)((r < 2048) ? r : r - 2048) * 2048;
    const float sgn = (r < 2048) ? 1.f : -1.f;
    const float* wrow = WT + (size_t)c * 2048;
    double s = 0.0;
#pragma unroll
    for (int it = 0; it < 8; it++) {
      const int k = (it * 64 + (int)lane) * 4;
      const float4 xv = *(const float4*)(xrow + k);
      const float4 wv = *(const float4*)(wrow + k);
      const float a0 = fmaxf(sgn * xv.x, 0.f);
      const float a1 = fmaxf(sgn * xv.y, 0.f);
      const float a2 = fmaxf(sgn * xv.z, 0.f);
      const float a3 = fmaxf(sgn * xv.w, 0.f);
      s += (double)a0 * (double)wv.x + (double)a1 * (double)wv.y +
           (double)a2 * (double)wv.z + (double)a3 * (double)wv.w;
    }
#pragma unroll
    for (int off = 32; off > 0; off >>= 1) s += __shfl_down(s, off);
    if (lane == 0) {
      double v = 0.0;
      unsigned m = 0;
#pragma unroll
      for (int t = 0; t < 10; t++) {
        v += s;
        if (v >= 1.0) { m |= (1u << t); v = 0.0; }
      }
      Mask[(size_t)r * 6144 + c] = (unsigned short)m;
    }
  }
}

// ---- K3: per-token spike attention (exact fp32), transpose (d,h)->d*16+h
__global__ __launch_bounds__(256) void spike_attn(const unsigned short* __restrict__ Mask,
                                                  float* __restrict__ xbar) {
  const int n = blockIdx.x;
  const int tid = threadIdx.x;

  __shared__ float xqT[128 * 17];  // [d][h], pad 17 -> conflict-free
  __shared__ float xkT[128 * 17];
  __shared__ float xvT[128 * 17];
  __shared__ float attnS[16 * 17];

  const unsigned short* mp = Mask + (size_t)n * 6144;
  const unsigned short* mn = Mask + (size_t)(n + 2048) * 6144;

  unsigned q_p[8], q_n[8], k_p[8], k_n[8], v_p[8], v_n[8];
#pragma unroll
  for (int j = 0; j < 8; j++) {
    const int c = tid + 256 * j;
    q_p[j] = mp[c];        q_n[j] = mn[c];
    k_p[j] = mp[2048 + c]; k_n[j] = mn[2048 + c];
    v_p[j] = mp[4096 + c]; v_n[j] = mn[4096 + c];
  }

  float acc[8];
#pragma unroll
  for (int j = 0; j < 8; j++) acc[j] = 0.f;

  for (int t = 0; t < 10; t++) {
#pragma unroll
    for (int j = 0; j < 8; j++) {
      const int c = tid + 256 * j;
      const int d = c & 127, h = c >> 7;
      const int a = d * 17 + h;
      xqT[a] = (float)((q_p[j] >> t) & 1u) - (float)((q_n[j] >> t) & 1u);
      xkT[a] = (float)((k_p[j] >> t) & 1u) - (float)((k_n[j] >> t) & 1u);
      xvT[a] = (float)((v_p[j] >> t) & 1u) - (float)((v_n[j] >> t) & 1u);
    }
    __syncthreads();

    {  // attn[h][m] = 0.125 * sum_d xq[h,d]*xk[m,d] — exact multiple of 1/8
      const int h = tid >> 4, m = tid & 15;
      float a = 0.f;
#pragma unroll
      for (int d = 0; d < 128; d++) a += xqT[d * 17 + h] * xkT[d * 17 + m];
      attnS[h * 17 + m] = a * 0.125f;
    }
    __syncthreads();

#pragma unroll
    for (int j = 0; j < 8; j++) {
      const int o = tid + 256 * j;
      const int h = o & 15, d = o >> 4;
      float s = 0.f;
#pragma unroll
      for (int m = 0; m < 16; m++) s += attnS[h * 17 + m] * xvT[d * 17 + m];
      acc[j] += s;
    }
    __syncthreads();
  }

#pragma unroll
  for (int j = 0; j < 8; j++) xbar[(size_t)n * 2048 + tid + 256 * j] = acc[j];
}

// ---- K4: out = (xbar @ wo) * 0.1, fp32 accumulation (safe: no decisions here)
__global__ __launch_bounds__(256) void gemm_out(const float* __restrict__ A,
                                                const float* __restrict__ W,
                                                float* __restrict__ C) {
  __shared__ float Ls[8][128];
  __shared__ float Rs[8][128];
  const int tid = threadIdx.x;
  const int row0 = blockIdx.y * 128, col0 = blockIdx.x * 128;

  const int am = tid >> 1, ak = (tid & 1) * 4;
  const int bk = tid >> 5, bj = (tid & 31) * 4;
  const int tx = tid & 15, ty = tid >> 4;

  float acc[8][8];
#pragma unroll
  for (int i = 0; i < 8; i++)
#pragma unroll
    for (int j = 0; j < 8; j++) acc[i][j] = 0.f;

  for (int k0 = 0; k0 < 2048; k0 += 8) {
    const float4 av = *(const float4*)(A + (size_t)(row0 + am) * 2048 + k0 + ak);
    Ls[ak + 0][am] = av.x;
    Ls[ak + 1][am] = av.y;
    Ls[ak + 2][am] = av.z;
    Ls[ak + 3][am] = av.w;
    const float4 bv = *(const float4*)(W + (size_t)(k0 + bk) * 2048 + col0 + bj);
    *(float4*)&Rs[bk][bj] = bv;
    __syncthreads();

#pragma unroll
    for (int kk = 0; kk < 8; kk++) {
      const float4 a0 = *(const float4*)&Ls[kk][ty * 4];
      const float4 a1 = *(const float4*)&Ls[kk][64 + ty * 4];
      const float4 b0 = *(const float4*)&Rs[kk][tx * 4];
      const float4 b1 = *(const float4*)&Rs[kk][64 + tx * 4];
      const float ar[8] = {a0.x, a0.y, a0.z, a0.w, a1.x, a1.y, a1.z, a1.w};
      const float br[8] = {b0.x, b0.y, b0.z, b0.w, b1.x, b1.y, b1.z, b1.w};
#pragma unroll
      for (int i = 0; i < 8; i++)
#pragma unroll
        for (int j = 0; j < 8; j++) acc[i][j] += ar[i] * br[j];
    }
    __syncthreads();
  }

#pragma unroll
  for (int i = 0; i < 8; i++) {
    const int r = row0 + ((i < 4) ? (ty * 4 + i) : (64 + ty * 4 + (i - 4)));
    float4 v0, v1;
    v0.x = acc[i][0] * 0.1f; v0.y = acc[i][1] * 0.1f;
    v0.z = acc[i][2] * 0.1f; v0.w = acc[i][3] * 0.1f;
    v1.x = acc[i][4] * 0.1f; v1.y = acc[i][5] * 0.1f;
    v1.z = acc[i][6] * 0.1f; v1.w = acc[i][7] * 0.1f;
    *(float4*)(C + (size_t)r * 2048 + col0 + tx * 4) = v0;
    *(float4*)(C + (size_t)r * 2048 + col0 + 64 + tx * 4) = v1;
  }
}

extern "C" void kernel_launch(void* const* d_in, const int* in_sizes, int n_in,
                              void* d_out, int out_size, void* d_ws, size_t ws_size,
                              hipStream_t stream) {
  const float* x = (const float*)d_in[0];
  // d_in[1] = freqs_cis (unused)
  const float* wq = (const float*)d_in[2];
  const float* wk = (const float*)d_in[3];
  const float* wv = (const float*)d_in[4];
  const float* wo = (const float*)d_in[5];
  float* out = (float*)d_out;

  char* ws = (char*)d_ws;
  unsigned short* Mask = (unsigned short*)ws;                       // 50.33 MB
  float* WT = (float*)(ws + (size_t)4096 * 6144 * 2);               // 50.33 MB
  float* xbar = WT;  // aliases WT (dead after rescue)
  unsigned* list = (unsigned*)(ws + (size_t)4096 * 6144 * 2 + (size_t)6144 * 2048 * 4);  // 8 MB
  unsigned* cnt = list + LIST_CAP;

  transpose_w<<<dim3(64, 192), dim3(32, 8), 0, stream>>>(wq, wk, wv, WT, cnt);
  gemm_spike<<<dim3(32, 32), 256, 0, stream>>>(x, WT, Mask, list, cnt);
  rescue<<<256, 256, 0, stream>>>(x, WT, list, cnt, Mask);
  spike_attn<<<2048, 256, 0, stream>>>(Mask, xbar);
  gemm_out<<<dim3(16, 16), 256, 0, stream>>>(xbar, wo, out);
}

// Round 5
// 1029.817 us; speedup vs baseline: 2.8086x; 1.7057x over previous
//
#include <hip/hip_runtime.h>
#include <hip/hip_bf16.h>

// Spiking attention, N=C=2048, T=10, heads=16, head_dim=128.
//
// Accuracy: every spike decision matches an fp64 pipeline. Bulk GEMM = bf16x2
// RNE-split MFMA (3 passes; sigma_dy ~ 3.5e-6); closed-form IF epilogue
// certifies each channel against FLAG_EPS=4e-4 (>=11 sigma vs 10x-amplified
// dy) or flags it; flagged channels (~0.5-1%) recomputed exactly in fp64.
//
//  K0 wsplit<1>:    wq|wk|wv -> Bpk (bf16x2 planes, packed per-(tile,k0) LDS
//                   images, XOR-swizzled chunks), zero cnt.
//  K1 gemm_mfma<0>: A = relu(+-x) converted in-loop; B via global_load_lds
//                   DMA of Bpk images; 3 MFMA passes; IF mask + certify/flag.
//  K2 transpose_w:  W^T f32 (over Bpk region) for rescue's coalesced dots.
//  K3 rescue:       fp64 dot per flagged channel (2048 blocks).
//  K4 spike_attn:   exact fp32 attention over spikes, (d,h)->d*16+h.
//  K5 wsplit<0>:    wo -> WOpk planes (over Mask region).
//  K6 gemm_mfma<1>: out = (xbar @ wo)*0.1 (xbar's 2-plane split is EXACT).
//
// ws layout (104.67 MB; 108.66 proven available):
//   [0      : Mask u16 50.33 MB | later WOpk 16.78 MB]
//   [50.33M : Bpk 50.33 MB | later WT f32 50.33 | later xbar f32 16.78]
//   [100.66M: list u32 4 MB][104.66M: cnt]

#define LIST_CAP (1u * 1024u * 1024u)
#define FLAG_EPS 4e-4f

typedef __attribute__((ext_vector_type(8))) short short8;
typedef __attribute__((ext_vector_type(4))) float floatx4;

__device__ const unsigned d_LUT[16] = {0u, 0x3FFu, 0x2AAu, 0x124u, 0x88u,
                                       0x210u, 0x20u, 0x40u, 0x80u, 0x100u,
                                       0x200u, 0u, 0u, 0u, 0u, 0u};

// RNE split f32 -> two bf16 planes (as raw u16).
__device__ __forceinline__ void bf16x2_rne(float a, unsigned& p1, unsigned& p2) {
  const unsigned u = __float_as_uint(a);
  const unsigned t1 = u + 0x7FFFu + ((u >> 16) & 1u);
  p1 = t1 >> 16;
  const float r = a - __uint_as_float(t1 & 0xFFFF0000u);
  const unsigned u2 = __float_as_uint(r);
  p2 = (u2 + 0x7FFFu + ((u2 >> 16) & 1u)) >> 16;
}

// ---- K0/K5: split W columns into packed, swizzled bf16 plane-tile images.
// Block (ct, k0i): image[plane][ct][k0i] = 128 rows (cols of W) x 32 k,
// row r at u16-offset r*32, chunk c (8 k) at 8*(c ^ ((r>>1)&3)).
template <int ZERO_CNT>
__global__ __launch_bounds__(256) void wsplit(
    const float* __restrict__ W0, const float* __restrict__ W1,
    const float* __restrict__ W2, unsigned short* __restrict__ Bpk,
    int NCT, unsigned* __restrict__ cnt) {
  if (ZERO_CNT && blockIdx.x == 0 && blockIdx.y == 0 && threadIdx.x == 0)
    *cnt = 0u;
  __shared__ float Wf[32 * 132];
  const int ct = blockIdx.x, k0 = blockIdx.y * 32;
  const int c0 = ct * 128;
  const int sel = c0 >> 11;
  const float* W = (sel == 0) ? W0 : ((sel == 1) ? W1 : W2);
  const int cc0 = c0 & 2047;
  const int t = threadIdx.x;

  const int kr = t >> 3, cq = (t & 7) * 16;
#pragma unroll
  for (int u = 0; u < 4; u++) {
    const float4 v = *(const float4*)(W + (size_t)(k0 + kr) * 2048 + cc0 + cq + 4 * u);
    *(float4*)&Wf[kr * 132 + cq + 4 * u] = v;
  }
  __syncthreads();

  const int cc = t >> 1, ch0 = (t & 1) * 2;
  unsigned short* img1 = Bpk + ((size_t)(0 * NCT + ct) * 64 + blockIdx.y) * 4096;
  unsigned short* img2 = Bpk + ((size_t)(1 * NCT + ct) * 64 + blockIdx.y) * 4096;
#pragma unroll
  for (int c = ch0; c < ch0 + 2; c++) {
    unsigned q1[8], q2[8];
#pragma unroll
    for (int e = 0; e < 8; e++) bf16x2_rne(Wf[(c * 8 + e) * 132 + cc], q1[e], q2[e]);
    const int off = cc * 32 + 8 * (c ^ ((cc >> 1) & 3));
    uint4 P1, P2;
    P1.x = q1[0] | (q1[1] << 16); P1.y = q1[2] | (q1[3] << 16);
    P1.z = q1[4] | (q1[5] << 16); P1.w = q1[6] | (q1[7] << 16);
    P2.x = q2[0] | (q2[1] << 16); P2.y = q2[2] | (q2[3] << 16);
    P2.z = q2[4] | (q2[5] << 16); P2.w = q2[6] | (q2[7] << 16);
    *(uint4*)&img1[off] = P1;
    *(uint4*)&img2[off] = P2;
  }
}

// ---- K1/K6: bf16x2 MFMA GEMM. 128x128 tile, BK=32, 2x2 waves (64x64/wave).
// MODE 0: A = relu(+-x), mask+certify epilogue. MODE 1: A = xbar, store *0.1.
template <int MODE>
__global__ __launch_bounds__(256) void gemm_mfma(
    const float* __restrict__ Xsrc, const unsigned short* __restrict__ Bpk,
    int NCT, unsigned short* __restrict__ Mask, unsigned* __restrict__ list,
    unsigned* __restrict__ cnt, float* __restrict__ Out) {
  __shared__ unsigned short Ash[2 * 4096];  // 2 planes x 8KB
  __shared__ unsigned short Bsh[2 * 4096];
  __shared__ unsigned lutS[16];

  const int tid = threadIdx.x;
  const int bx = blockIdx.x, by = blockIdx.y;
  if (MODE == 0 && tid < 16) lutS[tid] = d_LUT[tid];

  const int lane = tid & 63, wave = tid >> 6;
  const int wr = wave >> 1, wc = wave & 1;
  const int lm = lane & 15, lg = lane >> 4;

  float sgn = 1.f;
  const float* Xb;
  if (MODE == 0) {
    sgn = (by < 16) ? 1.f : -1.f;
    Xb = Xsrc + (size_t)((by < 16) ? by : by - 16) * 128 * 2048;
  } else {
    Xb = Xsrc + (size_t)by * 128 * 2048;
  }

  const int ar = tid >> 2, ac = tid & 3;  // A rows ar, ar+64; chunk ac

  floatx4 acc[4][4];
#pragma unroll
  for (int i = 0; i < 4; i++)
#pragma unroll
    for (int j = 0; j < 4; j++) acc[i][j] = (floatx4){0.f, 0.f, 0.f, 0.f};

  const int dmaP = wave >> 1, dmaH = wave & 1;

  for (int k0i = 0; k0i < 64; k0i++) {
    const int k0 = k0i * 32;
    __syncthreads();  // prior iteration's frag reads complete

    // B: DMA packed plane image -> LDS (wave covers 4KB = 4 x 1KB issues)
    {
      const unsigned short* gp =
          Bpk + (((size_t)dmaP * NCT + bx) * 64 + k0i) * 4096 + dmaH * 2048;
      unsigned short* lp = &Bsh[dmaP * 4096 + dmaH * 2048];
#pragma unroll
      for (int i = 0; i < 4; i++) {
        __builtin_amdgcn_global_load_lds(
            (const __attribute__((address_space(1))) unsigned*)(gp + i * 512 + lane * 8),
            (__attribute__((address_space(3))) unsigned*)(lp + i * 512), 16, 0, 0);
      }
    }

    // A: load f32, (relu), RNE-split, write swizzled planes
#pragma unroll
    for (int s = 0; s < 2; s++) {
      const int row = ar + 64 * s;
      const float* src = Xb + (size_t)row * 2048 + k0 + ac * 8;
      float4 v0 = ((const float4*)src)[0];
      float4 v1 = ((const float4*)src)[1];
      float f[8] = {v0.x, v0.y, v0.z, v0.w, v1.x, v1.y, v1.z, v1.w};
      if (MODE == 0) {
#pragma unroll
        for (int e = 0; e < 8; e++) f[e] = fmaxf(sgn * f[e], 0.f);
      }
      unsigned q1[8], q2[8];
#pragma unroll
      for (int e = 0; e < 8; e++) bf16x2_rne(f[e], q1[e], q2[e]);
      const int off = row * 32 + 8 * (ac ^ ((row >> 1) & 3));
      uint4 P1, P2;
      P1.x = q1[0] | (q1[1] << 16); P1.y = q1[2] | (q1[3] << 16);
      P1.z = q1[4] | (q1[5] << 16); P1.w = q1[6] | (q1[7] << 16);
      P2.x = q2[0] | (q2[1] << 16); P2.y = q2[2] | (q2[3] << 16);
      P2.z = q2[4] | (q2[5] << 16); P2.w = q2[6] | (q2[7] << 16);
      *(uint4*)&Ash[off] = P1;
      *(uint4*)&Ash[4096 + off] = P2;
    }
    __syncthreads();  // waits DMA (vmcnt) + LDS writes

    short8 a1[4], a2[4], b1[4], b2[4];
#pragma unroll
    for (int i = 0; i < 4; i++) {
      const int row = 64 * wr + 16 * i + lm;
      const int off = row * 32 + 8 * (lg ^ ((row >> 1) & 3));
      a1[i] = *(const short8*)&Ash[off];
      a2[i] = *(const short8*)&Ash[4096 + off];
    }
#pragma unroll
    for (int j = 0; j < 4; j++) {
      const int row = 64 * wc + 16 * j + lm;
      const int off = row * 32 + 8 * (lg ^ ((row >> 1) & 3));
      b1[j] = *(const short8*)&Bsh[off];
      b2[j] = *(const short8*)&Bsh[4096 + off];
    }
#pragma unroll
    for (int i = 0; i < 4; i++)
#pragma unroll
      for (int j = 0; j < 4; j++)
        acc[i][j] = __builtin_amdgcn_mfma_f32_16x16x32_bf16(a1[i], b1[j], acc[i][j], 0, 0, 0);
#pragma unroll
    for (int i = 0; i < 4; i++)
#pragma unroll
      for (int j = 0; j < 4; j++)
        acc[i][j] = __builtin_amdgcn_mfma_f32_16x16x32_bf16(a1[i], b2[j], acc[i][j], 0, 0, 0);
#pragma unroll
    for (int i = 0; i < 4; i++)
#pragma unroll
      for (int j = 0; j < 4; j++)
        acc[i][j] = __builtin_amdgcn_mfma_f32_16x16x32_bf16(a2[i], b1[j], acc[i][j], 0, 0, 0);
  }

  // C/D layout (m89): col = lane&15, row = (lane>>4)*4 + reg
#pragma unroll
  for (int i = 0; i < 4; i++) {
#pragma unroll
    for (int j = 0; j < 4; j++) {
      const int gn = bx * 128 + 64 * wc + 16 * j + lm;
#pragma unroll
      for (int vv = 0; vv < 4; vv++) {
        const int gm = by * 128 + 64 * wr + 16 * i + 4 * lg + vv;
        const float y = acc[i][j][vv];
        if (MODE == 1) {
          Out[(size_t)gm * 2048 + gn] = y * 0.1f;
        } else {
          float r = __builtin_amdgcn_rcpf(y);
          r = fminf(fmaxf(r, -1.0f), 12.0f);
          const float jf = floorf(r);
          const float d0 = fmaf(jf, y, -1.0f);
          const float i0 = fminf(fmaxf(jf, 1.0f), 10.0f);
          const float i1 = fminf(fmaxf(jf + 1.0f, 1.0f), 10.0f);
          const float e0 = fmaf(i0, y, -1.0f);
          const float e1 = fmaf(i1, y, -1.0f);
          const float mind = fminf(fabsf(e0), fabsf(e1));
          const int J = (int)((d0 >= 0.0f) ? jf : jf + 1.0f);
          const unsigned mask = (J <= 10) ? lutS[J & 15] : 0u;
          Mask[(size_t)gm * 6144 + gn] = (unsigned short)mask;
          if (mind < FLAG_EPS) {
            const unsigned idx = atomicAdd(cnt, 1u);
            if (idx < LIST_CAP) list[idx] = ((unsigned)gm << 13) | (unsigned)gn;
          }
        }
      }
    }
  }
}

// ---- K2: transpose W -> WT f32 (rescue source)
__global__ __launch_bounds__(256) void transpose_w(
    const float* __restrict__ W0, const float* __restrict__ W1,
    const float* __restrict__ W2, float* __restrict__ WT) {
  __shared__ float tile[32][33];
  const int k0 = blockIdx.x * 32;
  const int c0 = blockIdx.y * 32;
  const int sel = c0 >> 11;
  const float* W = (sel == 0) ? W0 : ((sel == 1) ? W1 : W2);
  const int cc0 = c0 & 2047;
  const int tx = threadIdx.x, ty = threadIdx.y;  // (32,8)
#pragma unroll
  for (int rep = 0; rep < 4; rep++)
    tile[ty + 8 * rep][tx] = W[(size_t)(k0 + ty + 8 * rep) * 2048 + cc0 + tx];
  __syncthreads();
#pragma unroll
  for (int rep = 0; rep < 4; rep++)
    WT[(size_t)(c0 + ty + 8 * rep) * 2048 + k0 + tx] = tile[tx][ty + 8 * rep];
}

// ---- K3: fp64 rescue of flagged channels (one wave per item)
__global__ __launch_bounds__(256) void rescue(
    const float* __restrict__ X, const float* __restrict__ WT,
    const unsigned* __restrict__ list, const unsigned* __restrict__ cnt,
    unsigned short* __restrict__ Mask) {
  const unsigned nItems = min(*cnt, LIST_CAP);
  const unsigned gtid = blockIdx.x * blockDim.x + threadIdx.x;
  const unsigned wave = gtid >> 6, lane = gtid & 63;
  const unsigned nWaves = (gridDim.x * blockDim.x) >> 6;

  for (unsigned i = wave; i < nItems; i += nWaves) {
    const unsigned e = list[i];
    const int r = (int)(e >> 13), c = (int)(e & 8191u);
    const float* xrow = X + (size_t)((r < 2048) ? r : r - 2048) * 2048;
    const float sg = (r < 2048) ? 1.f : -1.f;
    const float* wrow = WT + (size_t)c * 2048;
    double s = 0.0;
#pragma unroll
    for (int it = 0; it < 8; it++) {
      const int k = (it * 64 + (int)lane) * 4;
      const float4 xv = *(const float4*)(xrow + k);
      const float4 wv = *(const float4*)(wrow + k);
      const float a0 = fmaxf(sg * xv.x, 0.f);
      const float a1 = fmaxf(sg * xv.y, 0.f);
      const float a2 = fmaxf(sg * xv.z, 0.f);
      const float a3 = fmaxf(sg * xv.w, 0.f);
      s += (double)a0 * (double)wv.x + (double)a1 * (double)wv.y +
           (double)a2 * (double)wv.z + (double)a3 * (double)wv.w;
    }
#pragma unroll
    for (int off = 32; off > 0; off >>= 1) s += __shfl_down(s, off);
    if (lane == 0) {
      double v = 0.0;
      unsigned m = 0;
#pragma unroll
      for (int t = 0; t < 10; t++) {
        v += s;
        if (v >= 1.0) { m |= (1u << t); v = 0.0; }
      }
      Mask[(size_t)r * 6144 + c] = (unsigned short)m;
    }
  }
}

// ---- K4: per-token spike attention (exact fp32), transpose (d,h)->d*16+h
__global__ __launch_bounds__(256) void spike_attn(const unsigned short* __restrict__ Mask,
                                                  float* __restrict__ xbar) {
  const int n = blockIdx.x;
  const int tid = threadIdx.x;

  __shared__ float xqT[128 * 17];
  __shared__ float xkT[128 * 17];
  __shared__ float xvT[128 * 17];
  __shared__ float attnS[16 * 17];

  const unsigned short* mp = Mask + (size_t)n * 6144;
  const unsigned short* mn = Mask + (size_t)(n + 2048) * 6144;

  unsigned q_p[8], q_n[8], k_p[8], k_n[8], v_p[8], v_n[8];
#pragma unroll
  for (int j = 0; j < 8; j++) {
    const int c = tid + 256 * j;
    q_p[j] = mp[c];        q_n[j] = mn[c];
    k_p[j] = mp[2048 + c]; k_n[j] = mn[2048 + c];
    v_p[j] = mp[4096 + c]; v_n[j] = mn[4096 + c];
  }

  float acc[8];
#pragma unroll
  for (int j = 0; j < 8; j++) acc[j] = 0.f;

  for (int t = 0; t < 10; t++) {
#pragma unroll
    for (int j = 0; j < 8; j++) {
      const int c = tid + 256 * j;
      const int d = c & 127, h = c >> 7;
      const int a = d * 17 + h;
      xqT[a] = (float)((q_p[j] >> t) & 1u) - (float)((q_n[j] >> t) & 1u);
      xkT[a] = (float)((k_p[j] >> t) & 1u) - (float)((k_n[j] >> t) & 1u);
      xvT[a] = (float)((v_p[j] >> t) & 1u) - (float)((v_n[j] >> t) & 1u);
    }
    __syncthreads();

    {
      const int h = tid >> 4, m = tid & 15;
      float a = 0.f;
#pragma unroll
      for (int d = 0; d < 128; d++) a += xqT[d * 17 + h] * xkT[d * 17 + m];
      attnS[h * 17 + m] = a * 0.125f;
    }
    __syncthreads();

#pragma unroll
    for (int j = 0; j < 8; j++) {
      const int o = tid + 256 * j;
      const int h = o & 15, d = o >> 4;
      float s = 0.f;
#pragma unroll
      for (int m = 0; m < 16; m++) s += attnS[h * 17 + m] * xvT[d * 17 + m];
      acc[j] += s;
    }
    __syncthreads();
  }

#pragma unroll
  for (int j = 0; j < 8; j++) xbar[(size_t)n * 2048 + tid + 256 * j] = acc[j];
}

extern "C" void kernel_launch(void* const* d_in, const int* in_sizes, int n_in,
                              void* d_out, int out_size, void* d_ws, size_t ws_size,
                              hipStream_t stream) {
  const float* x = (const float*)d_in[0];
  // d_in[1] = freqs_cis (unused)
  const float* wq = (const float*)d_in[2];
  const float* wk = (const float*)d_in[3];
  const float* wv = (const float*)d_in[4];
  const float* wo = (const float*)d_in[5];
  float* out = (float*)d_out;

  char* ws = (char*)d_ws;
  unsigned short* Mask = (unsigned short*)ws;                 // 50.33 MB @0
  unsigned short* WOpk = (unsigned short*)ws;                 // 16.78 MB (after Mask dies)
  char* reg2 = ws + (size_t)4096 * 6144 * 2;                  // @50.33 MB
  unsigned short* Bpk = (unsigned short*)reg2;                // 50.33 MB
  float* WT = (float*)reg2;                                   // (after Bpk dies)
  float* xbar = (float*)reg2;                                 // (after WT dies)
  unsigned* list = (unsigned*)(reg2 + (size_t)6144 * 2048 * 4);  // 4 MB @100.66
  unsigned* cnt = list + LIST_CAP;

  wsplit<1><<<dim3(48, 64), 256, 0, stream>>>(wq, wk, wv, Bpk, 48, cnt);
  gemm_mfma<0><<<dim3(48, 32), 256, 0, stream>>>(x, Bpk, 48, Mask, list, cnt, nullptr);
  transpose_w<<<dim3(64, 192), dim3(32, 8), 0, stream>>>(wq, wk, wv, WT);
  rescue<<<2048, 256, 0, stream>>>(x, WT, list, cnt, Mask);
  spike_attn<<<2048, 256, 0, stream>>>(Mask, xbar);
  wsplit<0><<<dim3(16, 64), 256, 0, stream>>>(wo, wo, wo, WOpk, 16, nullptr);
  gemm_mfma<1><<<dim3(16, 16), 256, 0, stream>>>(xbar, WOpk, 16, nullptr, nullptr, nullptr, out);
}

// Round 6
// 932.917 us; speedup vs baseline: 3.1004x; 1.1039x over previous
//
#include <hip/hip_runtime.h>
#include <hip/hip_bf16.h>

// Spiking attention, N=C=2048, T=10, heads=16, head_dim=128.
//
// Accuracy: spike decisions match an fp64 pipeline. Bulk GEMMs are bf16x2
// RNE-split MFMA (3 passes a1b1+a1b2+a2b1; sigma_dy ~ 3.5e-6). Closed-form IF
// epilogue certifies each channel (FLAG_EPS=4e-4 >= 11 sigma of 10x-amplified
// dy) or flags it; flagged channels recomputed exactly in fp64 (rescue).
// For constant input the IF spike train is periodic with period J = first
// spike step, so masks are stored as J (u8); mask = LUT[J].
//
//  K1 wsplit<1>:   wq|wk|wv -> Bpk packed swizzled bf16x2 plane images; cnt=0.
//  K2 asplit<1>:   relu(+-x) -> Apk images (conversion done ONCE, not per bx).
//  K3 gemm_dma<0>: pure-DMA K-loop (global_load_lds for A and B planes),
//                  48 MFMA/iter, closed-form IF -> MaskJ u8 + certify/flag.
//  K4 transpose_w: W^T f32 for rescue.
//  K5 rescue:      fp64 dot per flagged channel -> J.
//  K6 spike_attn:  exact fp32 attention over spikes, (d,h)->d*16+h.
//  K7 wsplit<0>:   wo -> WOpk.   K8 asplit<0>: xbar -> Xbpk.
//  K9 gemm_dma<1>: out = (xbar @ wo)*0.1 (xbar's bf16x2 split is EXACT).
//
// ws layout (111.2 MB; >=117.4 proven in R1):
//   @0        MaskJ u8 25.17 MB   | after spike_attn: WOpk 16.78 MB
//   @25.17M   Bpk 50.33 MB        | after gemm<0>: WT f32 50.33
//                                 | after rescue: Xbpk 16.78
//   @75.50M   Apk 33.55 MB        | after gemm<0>: xbar f32 16.78
//   @109.05M  list u32 512K = 2 MB, then cnt u32

#define LIST_CAP (512u * 1024u)
#define FLAG_EPS 4e-4f

typedef __attribute__((ext_vector_type(8))) short short8;
typedef __attribute__((ext_vector_type(4))) float floatx4;

__device__ const unsigned d_LUT[16] = {0u, 0x3FFu, 0x2AAu, 0x124u, 0x88u,
                                       0x210u, 0x20u, 0x40u, 0x80u, 0x100u,
                                       0x200u, 0u, 0u, 0u, 0u, 0u};

// RNE split f32 -> two bf16 planes (raw u16 in low half).
__device__ __forceinline__ void bf16x2_rne(float a, unsigned& p1, unsigned& p2) {
  const unsigned u = __float_as_uint(a);
  const unsigned t1 = u + 0x7FFFu + ((u >> 16) & 1u);
  p1 = t1 >> 16;
  const float r = a - __uint_as_float(t1 & 0xFFFF0000u);
  const unsigned u2 = __float_as_uint(r);
  p2 = (u2 + 0x7FFFu + ((u2 >> 16) & 1u)) >> 16;
}

// ---- wsplit: W columns -> packed swizzled plane-tile images (image row =
// W column). Image (plane,ct,k0i): row r at r*32 shorts, chunk c (8 shorts)
// at 8*(c ^ ((r>>1)&3)).
template <int ZERO_CNT>
__global__ __launch_bounds__(256) void wsplit(
    const float* __restrict__ W0, const float* __restrict__ W1,
    const float* __restrict__ W2, unsigned short* __restrict__ Bpk,
    int NCT, unsigned* __restrict__ cnt) {
  if (ZERO_CNT && blockIdx.x == 0 && blockIdx.y == 0 && threadIdx.x == 0)
    *cnt = 0u;
  __shared__ float Wf[32 * 132];
  const int ct = blockIdx.x, k0 = blockIdx.y * 32;
  const int c0 = ct * 128;
  const int sel = c0 >> 11;
  const float* W = (sel == 0) ? W0 : ((sel == 1) ? W1 : W2);
  const int cc0 = c0 & 2047;
  const int t = threadIdx.x;

  const int kr = t >> 3, cq = (t & 7) * 16;
#pragma unroll
  for (int u = 0; u < 4; u++) {
    const float4 v = *(const float4*)(W + (size_t)(k0 + kr) * 2048 + cc0 + cq + 4 * u);
    *(float4*)&Wf[kr * 132 + cq + 4 * u] = v;
  }
  __syncthreads();

  const int cc = t >> 1, ch0 = (t & 1) * 2;
  unsigned short* img1 = Bpk + ((size_t)(0 * NCT + ct) * 64 + blockIdx.y) * 4096;
  unsigned short* img2 = Bpk + ((size_t)(1 * NCT + ct) * 64 + blockIdx.y) * 4096;
#pragma unroll
  for (int c = ch0; c < ch0 + 2; c++) {
    unsigned q1[8], q2[8];
#pragma unroll
    for (int e = 0; e < 8; e++) bf16x2_rne(Wf[(c * 8 + e) * 132 + cc], q1[e], q2[e]);
    const int off = cc * 32 + 8 * (c ^ ((cc >> 1) & 3));
    uint4 P1, P2;
    P1.x = q1[0] | (q1[1] << 16); P1.y = q1[2] | (q1[3] << 16);
    P1.z = q1[4] | (q1[5] << 16); P1.w = q1[6] | (q1[7] << 16);
    P2.x = q2[0] | (q2[1] << 16); P2.y = q2[2] | (q2[3] << 16);
    P2.z = q2[4] | (q2[5] << 16); P2.w = q2[6] | (q2[7] << 16);
    *(uint4*)&img1[off] = P1;
    *(uint4*)&img2[off] = P2;
  }
}

// ---- asplit: row-major A (optionally relu(+-)) -> packed swizzled images.
template <int RELU>
__global__ __launch_bounds__(256) void asplit(
    const float* __restrict__ src, unsigned short* __restrict__ Apk, int NRT) {
  const int rt = blockIdx.x, k0i = blockIdx.y;
  const int t = threadIdx.x;
  const int r = t >> 1, half = t & 1;
  int grow = rt * 128 + r;
  float sgn = 1.f;
  if (RELU && grow >= 2048) { grow -= 2048; sgn = -1.f; }
  const float* s = src + (size_t)grow * 2048 + k0i * 32 + half * 16;
  float f[16];
#pragma unroll
  for (int u = 0; u < 4; u++) {
    const float4 v = *(const float4*)(s + 4 * u);
    f[4 * u + 0] = v.x; f[4 * u + 1] = v.y;
    f[4 * u + 2] = v.z; f[4 * u + 3] = v.w;
  }
  if (RELU) {
#pragma unroll
    for (int e = 0; e < 16; e++) f[e] = fmaxf(sgn * f[e], 0.f);
  }
  unsigned q1[16], q2[16];
#pragma unroll
  for (int e = 0; e < 16; e++) bf16x2_rne(f[e], q1[e], q2[e]);

  unsigned short* img1 = Apk + ((size_t)(0 * NRT + rt) * 64 + k0i) * 4096;
  unsigned short* img2 = Apk + ((size_t)(1 * NRT + rt) * 64 + k0i) * 4096;
#pragma unroll
  for (int cc = 0; cc < 2; cc++) {
    const int c = half * 2 + cc;
    const int off = r * 32 + 8 * (c ^ ((r >> 1) & 3));
    const int e0 = cc * 8;
    uint4 P1, P2;
    P1.x = q1[e0 + 0] | (q1[e0 + 1] << 16); P1.y = q1[e0 + 2] | (q1[e0 + 3] << 16);
    P1.z = q1[e0 + 4] | (q1[e0 + 5] << 16); P1.w = q1[e0 + 6] | (q1[e0 + 7] << 16);
    P2.x = q2[e0 + 0] | (q2[e0 + 1] << 16); P2.y = q2[e0 + 2] | (q2[e0 + 3] << 16);
    P2.z = q2[e0 + 4] | (q2[e0 + 5] << 16); P2.w = q2[e0 + 6] | (q2[e0 + 7] << 16);
    *(uint4*)&img1[off] = P1;
    *(uint4*)&img2[off] = P2;
  }
}

// ---- gemm_dma: pure-DMA bf16x2 MFMA GEMM, 128x128 tile, BK=32, 2x2 waves.
// MODE 0: closed-form IF -> MaskJ u8 + certify/flag. MODE 1: store y*0.1.
template <int MODE>
__global__ __launch_bounds__(256) void gemm_dma(
    const unsigned short* __restrict__ Apk, const unsigned short* __restrict__ Bpk,
    int NRT, int NCT, unsigned char* __restrict__ MaskJ,
    unsigned* __restrict__ list, unsigned* __restrict__ cnt,
    float* __restrict__ Out) {
  __shared__ unsigned short sh[4][4096];  // A p1, A p2, B p1, B p2

  const int tid = threadIdx.x;
  const int bx = blockIdx.x, by = blockIdx.y;
  const int lane = tid & 63, wave = tid >> 6;
  const int wr = wave >> 1, wc = wave & 1;
  const int lm = lane & 15, lg = lane >> 4;

  // each wave DMAs one image per k-step
  const unsigned short* gsrc =
      (wave < 2) ? (Apk + ((size_t)(wave * NRT + by) * 64) * 4096)
                 : (Bpk + ((size_t)((wave - 2) * NCT + bx) * 64) * 4096);

  floatx4 acc[4][4];
#pragma unroll
  for (int i = 0; i < 4; i++)
#pragma unroll
    for (int j = 0; j < 4; j++) acc[i][j] = (floatx4){0.f, 0.f, 0.f, 0.f};

  for (int k0i = 0; k0i < 64; k0i++) {
    __syncthreads();  // prior iteration's fragment reads complete
    const unsigned short* gp = gsrc + (size_t)k0i * 4096;
#pragma unroll
    for (int i = 0; i < 8; i++) {
      __builtin_amdgcn_global_load_lds(
          (const __attribute__((address_space(1))) unsigned*)(gp + i * 512 + lane * 8),
          (__attribute__((address_space(3))) unsigned*)(&sh[wave][i * 512]), 16, 0, 0);
    }
    __syncthreads();  // drains vmcnt -> DMA landed

    short8 a1[4], a2[4], b1[4], b2[4];
#pragma unroll
    for (int i = 0; i < 4; i++) {
      const int row = 64 * wr + 16 * i + lm;
      const int off = row * 32 + 8 * (lg ^ ((row >> 1) & 3));
      a1[i] = *(const short8*)&sh[0][off];
      a2[i] = *(const short8*)&sh[1][off];
    }
#pragma unroll
    for (int j = 0; j < 4; j++) {
      const int row = 64 * wc + 16 * j + lm;
      const int off = row * 32 + 8 * (lg ^ ((row >> 1) & 3));
      b1[j] = *(const short8*)&sh[2][off];
      b2[j] = *(const short8*)&sh[3][off];
    }
#pragma unroll
    for (int i = 0; i < 4; i++)
#pragma unroll
      for (int j = 0; j < 4; j++)
        acc[i][j] = __builtin_amdgcn_mfma_f32_16x16x32_bf16(a1[i], b1[j], acc[i][j], 0, 0, 0);
#pragma unroll
    for (int i = 0; i < 4; i++)
#pragma unroll
      for (int j = 0; j < 4; j++)
        acc[i][j] = __builtin_amdgcn_mfma_f32_16x16x32_bf16(a1[i], b2[j], acc[i][j], 0, 0, 0);
#pragma unroll
    for (int i = 0; i < 4; i++)
#pragma unroll
      for (int j = 0; j < 4; j++)
        acc[i][j] = __builtin_amdgcn_mfma_f32_16x16x32_bf16(a2[i], b1[j], acc[i][j], 0, 0, 0);
  }

  // C/D layout (m89): col = lane&15, row = (lane>>4)*4 + reg
#pragma unroll
  for (int i = 0; i < 4; i++) {
#pragma unroll
    for (int j = 0; j < 4; j++) {
      const int gn = bx * 128 + 64 * wc + 16 * j + lm;
#pragma unroll
      for (int vv = 0; vv < 4; vv++) {
        const int gm = by * 128 + 64 * wr + 16 * i + 4 * lg + vv;
        const float y = acc[i][j][vv];
        if (MODE == 1) {
          Out[(size_t)gm * 2048 + gn] = y * 0.1f;
        } else {
          float r = __builtin_amdgcn_rcpf(y);
          r = fminf(fmaxf(r, -1.0f), 12.0f);
          const float jf = floorf(r);
          const float d0 = fmaf(jf, y, -1.0f);
          const float i0 = fminf(fmaxf(jf, 1.0f), 10.0f);
          const float i1 = fminf(fmaxf(jf + 1.0f, 1.0f), 10.0f);
          const float e0 = fmaf(i0, y, -1.0f);
          const float e1 = fmaf(i1, y, -1.0f);
          const float mind = fminf(fabsf(e0), fabsf(e1));
          const unsigned J = (unsigned)(int)((d0 >= 0.0f) ? jf : jf + 1.0f);
          MaskJ[(size_t)gm * 6144 + gn] = (unsigned char)((J <= 10u) ? J : 0u);
          if (mind < FLAG_EPS) {
            const unsigned idx = atomicAdd(cnt, 1u);
            if (idx < LIST_CAP) list[idx] = ((unsigned)gm << 13) | (unsigned)gn;
          }
        }
      }
    }
  }
}

// ---- transpose W -> WT f32 (rescue source)
__global__ __launch_bounds__(256) void transpose_w(
    const float* __restrict__ W0, const float* __restrict__ W1,
    const float* __restrict__ W2, float* __restrict__ WT) {
  __shared__ float tile[32][33];
  const int k0 = blockIdx.x * 32;
  const int c0 = blockIdx.y * 32;
  const int sel = c0 >> 11;
  const float* W = (sel == 0) ? W0 : ((sel == 1) ? W1 : W2);
  const int cc0 = c0 & 2047;
  const int tx = threadIdx.x, ty = threadIdx.y;  // (32,8)
#pragma unroll
  for (int rep = 0; rep < 4; rep++)
    tile[ty + 8 * rep][tx] = W[(size_t)(k0 + ty + 8 * rep) * 2048 + cc0 + tx];
  __syncthreads();
#pragma unroll
  for (int rep = 0; rep < 4; rep++)
    WT[(size_t)(c0 + ty + 8 * rep) * 2048 + k0 + tx] = tile[tx][ty + 8 * rep];
}

// ---- rescue: fp64 dot for flagged channels -> first-spike J (u8)
__global__ __launch_bounds__(256) void rescue(
    const float* __restrict__ X, const float* __restrict__ WT,
    const unsigned* __restrict__ list, const unsigned* __restrict__ cnt,
    unsigned char* __restrict__ MaskJ) {
  const unsigned nItems = min(*cnt, LIST_CAP);
  const unsigned gtid = blockIdx.x * blockDim.x + threadIdx.x;
  const unsigned wave = gtid >> 6, lane = gtid & 63;
  const unsigned nWaves = (gridDim.x * blockDim.x) >> 6;

  for (unsigned i = wave; i < nItems; i += nWaves) {
    const unsigned e = list[i];
    const int r = (int)(e >> 13), c = (int)(e & 8191u);
    const float* xrow = X + (size_t)((r < 2048) ? r : r - 2048) * 2048;
    const float sg = (r < 2048) ? 1.f : -1.f;
    const float* wrow = WT + (size_t)c * 2048;
    double s = 0.0;
#pragma unroll
    for (int it = 0; it < 8; it++) {
      const int k = (it * 64 + (int)lane) * 4;
      const float4 xv = *(const float4*)(xrow + k);
      const float4 wv = *(const float4*)(wrow + k);
      const float a0 = fmaxf(sg * xv.x, 0.f);
      const float a1 = fmaxf(sg * xv.y, 0.f);
      const float a2 = fmaxf(sg * xv.z, 0.f);
      const float a3 = fmaxf(sg * xv.w, 0.f);
      s += (double)a0 * (double)wv.x + (double)a1 * (double)wv.y +
           (double)a2 * (double)wv.z + (double)a3 * (double)wv.w;
    }
#pragma unroll
    for (int off = 32; off > 0; off >>= 1) s += __shfl_down(s, off);
    if (lane == 0) {
      double v = 0.0;
      unsigned J = 0;
#pragma unroll
      for (int t = 0; t < 10; t++) {
        v += s;
        if (J == 0u && v >= 1.0) J = (unsigned)(t + 1);
      }
      MaskJ[(size_t)r * 6144 + c] = (unsigned char)J;
    }
  }
}

// ---- spike_attn: per-token exact fp32 attention, transpose (d,h)->d*16+h
__global__ __launch_bounds__(256) void spike_attn(const unsigned char* __restrict__ MaskJ,
                                                  float* __restrict__ xbar) {
  const int n = blockIdx.x;
  const int tid = threadIdx.x;

  __shared__ float xqT[128 * 17];
  __shared__ float xkT[128 * 17];
  __shared__ float xvT[128 * 17];
  __shared__ float attnS[16 * 17];
  __shared__ unsigned lutS[16];

  if (tid < 16) lutS[tid] = d_LUT[tid];
  __syncthreads();

  const unsigned char* mp = MaskJ + (size_t)n * 6144;
  const unsigned char* mn = MaskJ + (size_t)(n + 2048) * 6144;

  unsigned q_p[8], q_n[8], k_p[8], k_n[8], v_p[8], v_n[8];
#pragma unroll
  for (int j = 0; j < 8; j++) {
    const int c = tid + 256 * j;
    q_p[j] = lutS[mp[c]];        q_n[j] = lutS[mn[c]];
    k_p[j] = lutS[mp[2048 + c]]; k_n[j] = lutS[mn[2048 + c]];
    v_p[j] = lutS[mp[4096 + c]]; v_n[j] = lutS[mn[4096 + c]];
  }

  float acc[8];
#pragma unroll
  for (int j = 0; j < 8; j++) acc[j] = 0.f;

  for (int t = 0; t < 10; t++) {
#pragma unroll
    for (int j = 0; j < 8; j++) {
      const int c = tid + 256 * j;
      const int d = c & 127, h = c >> 7;
      const int a = d * 17 + h;
      xqT[a] = (float)((q_p[j] >> t) & 1u) - (float)((q_n[j] >> t) & 1u);
      xkT[a] = (float)((k_p[j] >> t) & 1u) - (float)((k_n[j] >> t) & 1u);
      xvT[a] = (float)((v_p[j] >> t) & 1u) - (float)((v_n[j] >> t) & 1u);
    }
    __syncthreads();

    {
      const int h = tid >> 4, m = tid & 15;
      float a = 0.f;
#pragma unroll
      for (int d = 0; d < 128; d++) a += xqT[d * 17 + h] * xkT[d * 17 + m];
      attnS[h * 17 + m] = a * 0.125f;
    }
    __syncthreads();

#pragma unroll
    for (int j = 0; j < 8; j++) {
      const int o = tid + 256 * j;
      const int h = o & 15, d = o >> 4;
      float s = 0.f;
#pragma unroll
      for (int m = 0; m < 16; m++) s += attnS[h * 17 + m] * xvT[d * 17 + m];
      acc[j] += s;
    }
    __syncthreads();
  }

#pragma unroll
  for (int j = 0; j < 8; j++) xbar[(size_t)n * 2048 + tid + 256 * j] = acc[j];
}

extern "C" void kernel_launch(void* const* d_in, const int* in_sizes, int n_in,
                              void* d_out, int out_size, void* d_ws, size_t ws_size,
                              hipStream_t stream) {
  const float* x = (const float*)d_in[0];
  // d_in[1] = freqs_cis (unused)
  const float* wq = (const float*)d_in[2];
  const float* wk = (const float*)d_in[3];
  const float* wv = (const float*)d_in[4];
  const float* wo = (const float*)d_in[5];
  float* out = (float*)d_out;

  char* ws = (char*)d_ws;
  unsigned char* MaskJ = (unsigned char*)ws;                       // 25.17 MB @0
  unsigned short* WOpk = (unsigned short*)ws;                      // 16.78 MB (MaskJ dead)
  char* reg2 = ws + (size_t)4096 * 6144;                           // @25.17 MB
  unsigned short* Bpk = (unsigned short*)reg2;                     // 50.33 MB
  float* WT = (float*)reg2;                                        // (Bpk dead)
  unsigned short* Xbpk = (unsigned short*)reg2;                    // 16.78 MB (WT dead)
  char* reg3 = reg2 + (size_t)6144 * 2048 * 2 * 2;                 // @75.50 MB
  unsigned short* Apk = (unsigned short*)reg3;                     // 33.55 MB
  float* xbar = (float*)reg3;                                      // 16.78 MB (Apk dead)
  unsigned* list = (unsigned*)(reg3 + (size_t)4096 * 2048 * 2 * 2);  // 2 MB @109.05
  unsigned* cnt = list + LIST_CAP;

  wsplit<1><<<dim3(48, 64), 256, 0, stream>>>(wq, wk, wv, Bpk, 48, cnt);
  asplit<1><<<dim3(32, 64), 256, 0, stream>>>(x, Apk, 32);
  gemm_dma<0><<<dim3(48, 32), 256, 0, stream>>>(Apk, Bpk, 32, 48, MaskJ, list, cnt, nullptr);
  transpose_w<<<dim3(64, 192), dim3(32, 8), 0, stream>>>(wq, wk, wv, WT);
  rescue<<<2048, 256, 0, stream>>>(x, WT, list, cnt, MaskJ);
  spike_attn<<<2048, 256, 0, stream>>>(MaskJ, xbar);
  wsplit<0><<<dim3(16, 64), 256, 0, stream>>>(wo, wo, wo, WOpk, 16, nullptr);
  asplit<0><<<dim3(16, 64), 256, 0, stream>>>(xbar, Xbpk, 16);
  gemm_dma<1><<<dim3(16, 16), 256, 0, stream>>>(Xbpk, WOpk, 16, 16, nullptr, nullptr, nullptr, out);
}

// Round 7
// 838.550 us; speedup vs baseline: 3.4493x; 1.1125x over previous
//
#include <hip/hip_runtime.h>
#include <hip/hip_bf16.h>

// Spiking attention, N=C=2048, T=10, heads=16, head_dim=128.
//
// Accuracy: spike decisions match an fp64 pipeline. Bulk GEMMs are bf16x2
// RNE-split MFMA (3 passes a1b1+a1b2+a2b1; sigma_dy ~ 3.5e-6). Closed-form IF
// epilogue certifies each channel (FLAG_EPS=4e-4 >= 11 sigma of 10x-amplified
// dy) or flags it; flagged channels recomputed exactly in fp64 (rescue).
// Constant input => IF spike train periodic with period J = first spike step;
// masks stored as J (u8); mask = LUT[J].
//
//  K1 wsplit<1>:   wq|wk|wv -> Bpk packed swizzled bf16x2 plane images; cnt=0.
//  K2 asplit<1>:   relu(+-x) -> Apk images (conversion done ONCE).
//  K3 gemm_dma<0>: double-buffered pure-DMA K-loop (DMA(k+1) in flight during
//                  compute(k)), 48 MFMA/iter, closed-form IF -> MaskJ + flags.
//  K4 transpose_w: W^T f32 for rescue.
//  K5 rescue:      fp64 dot per flagged channel -> J.
//  K6 spike_attn:  ballot-bitpack + popcount QK (exact), float PV, (d,h)->d*16+h.
//  K7 wsplit<0>:   wo -> WOpk.   K8 asplit<0>: xbar -> Xbpk (split exact).
//  K9 gemm_dma<1>: out = (xbar @ wo)*0.1.
//
// ws layout (111.2 MB; >=117.4 proven in R1):
//   @0        MaskJ u8 25.17 MB   | after spike_attn: WOpk 16.78 MB
//   @25.17M   Bpk 50.33 MB        | after gemm<0>: WT f32 50.33
//                                 | after rescue: Xbpk 16.78
//   @75.50M   Apk 33.55 MB        | after gemm<0>: xbar f32 16.78
//   @109.05M  list u32 512K = 2 MB, then cnt u32

#define LIST_CAP (512u * 1024u)
#define FLAG_EPS 4e-4f

typedef __attribute__((ext_vector_type(8))) short short8;
typedef __attribute__((ext_vector_type(4))) float floatx4;

__device__ const unsigned d_LUT[16] = {0u, 0x3FFu, 0x2AAu, 0x124u, 0x88u,
                                       0x210u, 0x20u, 0x40u, 0x80u, 0x100u,
                                       0x200u, 0u, 0u, 0u, 0u, 0u};

// RNE split f32 -> two bf16 planes (raw u16 in low half).
__device__ __forceinline__ void bf16x2_rne(float a, unsigned& p1, unsigned& p2) {
  const unsigned u = __float_as_uint(a);
  const unsigned t1 = u + 0x7FFFu + ((u >> 16) & 1u);
  p1 = t1 >> 16;
  const float r = a - __uint_as_float(t1 & 0xFFFF0000u);
  const unsigned u2 = __float_as_uint(r);
  p2 = (u2 + 0x7FFFu + ((u2 >> 16) & 1u)) >> 16;
}

// ---- wsplit: W columns -> packed swizzled plane-tile images (image row =
// W column). Image (plane,ct,k0i): row r at r*32 shorts, chunk c (8 shorts)
// at 8*(c ^ ((r>>1)&3)).
template <int ZERO_CNT>
__global__ __launch_bounds__(256) void wsplit(
    const float* __restrict__ W0, const float* __restrict__ W1,
    const float* __restrict__ W2, unsigned short* __restrict__ Bpk,
    int NCT, unsigned* __restrict__ cnt) {
  if (ZERO_CNT && blockIdx.x == 0 && blockIdx.y == 0 && threadIdx.x == 0)
    *cnt = 0u;
  __shared__ float Wf[32 * 132];
  const int ct = blockIdx.x, k0 = blockIdx.y * 32;
  const int c0 = ct * 128;
  const int sel = c0 >> 11;
  const float* W = (sel == 0) ? W0 : ((sel == 1) ? W1 : W2);
  const int cc0 = c0 & 2047;
  const int t = threadIdx.x;

  const int kr = t >> 3, cq = (t & 7) * 16;
#pragma unroll
  for (int u = 0; u < 4; u++) {
    const float4 v = *(const float4*)(W + (size_t)(k0 + kr) * 2048 + cc0 + cq + 4 * u);
    *(float4*)&Wf[kr * 132 + cq + 4 * u] = v;
  }
  __syncthreads();

  const int cc = t >> 1, ch0 = (t & 1) * 2;
  unsigned short* img1 = Bpk + ((size_t)(0 * NCT + ct) * 64 + blockIdx.y) * 4096;
  unsigned short* img2 = Bpk + ((size_t)(1 * NCT + ct) * 64 + blockIdx.y) * 4096;
#pragma unroll
  for (int c = ch0; c < ch0 + 2; c++) {
    unsigned q1[8], q2[8];
#pragma unroll
    for (int e = 0; e < 8; e++) bf16x2_rne(Wf[(c * 8 + e) * 132 + cc], q1[e], q2[e]);
    const int off = cc * 32 + 8 * (c ^ ((cc >> 1) & 3));
    uint4 P1, P2;
    P1.x = q1[0] | (q1[1] << 16); P1.y = q1[2] | (q1[3] << 16);
    P1.z = q1[4] | (q1[5] << 16); P1.w = q1[6] | (q1[7] << 16);
    P2.x = q2[0] | (q2[1] << 16); P2.y = q2[2] | (q2[3] << 16);
    P2.z = q2[4] | (q2[5] << 16); P2.w = q2[6] | (q2[7] << 16);
    *(uint4*)&img1[off] = P1;
    *(uint4*)&img2[off] = P2;
  }
}

// ---- asplit: row-major A (optionally relu(+-)) -> packed swizzled images.
template <int RELU>
__global__ __launch_bounds__(256) void asplit(
    const float* __restrict__ src, unsigned short* __restrict__ Apk, int NRT) {
  const int rt = blockIdx.x, k0i = blockIdx.y;
  const int t = threadIdx.x;
  const int r = t >> 1, half = t & 1;
  int grow = rt * 128 + r;
  float sgn = 1.f;
  if (RELU && grow >= 2048) { grow -= 2048; sgn = -1.f; }
  const float* s = src + (size_t)grow * 2048 + k0i * 32 + half * 16;
  float f[16];
#pragma unroll
  for (int u = 0; u < 4; u++) {
    const float4 v = *(const float4*)(s + 4 * u);
    f[4 * u + 0] = v.x; f[4 * u + 1] = v.y;
    f[4 * u + 2] = v.z; f[4 * u + 3] = v.w;
  }
  if (RELU) {
#pragma unroll
    for (int e = 0; e < 16; e++) f[e] = fmaxf(sgn * f[e], 0.f);
  }
  unsigned q1[16], q2[16];
#pragma unroll
  for (int e = 0; e < 16; e++) bf16x2_rne(f[e], q1[e], q2[e]);

  unsigned short* img1 = Apk + ((size_t)(0 * NRT + rt) * 64 + k0i) * 4096;
  unsigned short* img2 = Apk + ((size_t)(1 * NRT + rt) * 64 + k0i) * 4096;
#pragma unroll
  for (int cc = 0; cc < 2; cc++) {
    const int c = half * 2 + cc;
    const int off = r * 32 + 8 * (c ^ ((r >> 1) & 3));
    const int e0 = cc * 8;
    uint4 P1, P2;
    P1.x = q1[e0 + 0] | (q1[e0 + 1] << 16); P1.y = q1[e0 + 2] | (q1[e0 + 3] << 16);
    P1.z = q1[e0 + 4] | (q1[e0 + 5] << 16); P1.w = q1[e0 + 6] | (q1[e0 + 7] << 16);
    P2.x = q2[e0 + 0] | (q2[e0 + 1] << 16); P2.y = q2[e0 + 2] | (q2[e0 + 3] << 16);
    P2.z = q2[e0 + 4] | (q2[e0 + 5] << 16); P2.w = q2[e0 + 6] | (q2[e0 + 7] << 16);
    *(uint4*)&img1[off] = P1;
    *(uint4*)&img2[off] = P2;
  }
}

// ---- gemm_dma: double-buffered pure-DMA bf16x2 MFMA GEMM. 128x128 tile,
// BK=32, 2x2 waves. Loop shape: barrier(waits DMA(k)) -> issue DMA(k+1) into
// other buffer -> frag-read+MFMA on buffer k. DMA(k+1) is in flight during
// the whole compute phase (the m97 overlap).
// MODE 0: closed-form IF -> MaskJ u8 + certify/flag. MODE 1: store y*0.1.
template <int MODE>
__global__ __launch_bounds__(256) void gemm_dma(
    const unsigned short* __restrict__ Apk, const unsigned short* __restrict__ Bpk,
    int NRT, int NCT, unsigned char* __restrict__ MaskJ,
    unsigned* __restrict__ list, unsigned* __restrict__ cnt,
    float* __restrict__ Out) {
  __shared__ unsigned short sh[2][4][4096];  // [buf][A p1, A p2, B p1, B p2]
  __shared__ unsigned lutS[16];

  const int tid = threadIdx.x;
  const int bx = blockIdx.x, by = blockIdx.y;
  const int lane = tid & 63, wave = tid >> 6;
  const int wr = wave >> 1, wc = wave & 1;
  const int lm = lane & 15, lg = lane >> 4;

  if (MODE == 0 && tid < 16) lutS[tid] = d_LUT[tid];

  // each wave DMAs one 8 KB image per k-step
  const unsigned short* gsrc =
      (wave < 2) ? (Apk + ((size_t)(wave * NRT + by) * 64) * 4096)
                 : (Bpk + ((size_t)((wave - 2) * NCT + bx) * 64) * 4096);

  auto dma8 = [&](unsigned short* dst, const unsigned short* src) {
#pragma unroll
    for (int i = 0; i < 8; i++) {
      __builtin_amdgcn_global_load_lds(
          (const __attribute__((address_space(1))) unsigned*)(src + i * 512 + lane * 8),
          (__attribute__((address_space(3))) unsigned*)(dst + i * 512), 16, 0, 0);
    }
  };

  floatx4 acc[4][4];
#pragma unroll
  for (int i = 0; i < 4; i++)
#pragma unroll
    for (int j = 0; j < 4; j++) acc[i][j] = (floatx4){0.f, 0.f, 0.f, 0.f};

  dma8(&sh[0][wave][0], gsrc);  // prefetch k0i = 0

  for (int k0i = 0; k0i < 64; k0i++) {
    __syncthreads();  // drains vmcnt -> DMA(k0i) landed; orders prior frag reads
    if (k0i + 1 < 64)
      dma8(&sh[(k0i + 1) & 1][wave][0], gsrc + (size_t)(k0i + 1) * 4096);

    const unsigned short(*cur)[4096] = sh[k0i & 1];
    short8 a1[4], a2[4], b1[4], b2[4];
#pragma unroll
    for (int i = 0; i < 4; i++) {
      const int row = 64 * wr + 16 * i + lm;
      const int off = row * 32 + 8 * (lg ^ ((row >> 1) & 3));
      a1[i] = *(const short8*)&cur[0][off];
      a2[i] = *(const short8*)&cur[1][off];
    }
#pragma unroll
    for (int j = 0; j < 4; j++) {
      const int row = 64 * wc + 16 * j + lm;
      const int off = row * 32 + 8 * (lg ^ ((row >> 1) & 3));
      b1[j] = *(const short8*)&cur[2][off];
      b2[j] = *(const short8*)&cur[3][off];
    }
#pragma unroll
    for (int i = 0; i < 4; i++)
#pragma unroll
      for (int j = 0; j < 4; j++)
        acc[i][j] = __builtin_amdgcn_mfma_f32_16x16x32_bf16(a1[i], b1[j], acc[i][j], 0, 0, 0);
#pragma unroll
    for (int i = 0; i < 4; i++)
#pragma unroll
      for (int j = 0; j < 4; j++)
        acc[i][j] = __builtin_amdgcn_mfma_f32_16x16x32_bf16(a1[i], b2[j], acc[i][j], 0, 0, 0);
#pragma unroll
    for (int i = 0; i < 4; i++)
#pragma unroll
      for (int j = 0; j < 4; j++)
        acc[i][j] = __builtin_amdgcn_mfma_f32_16x16x32_bf16(a2[i], b1[j], acc[i][j], 0, 0, 0);
  }

  // C/D layout (m89): col = lane&15, row = (lane>>4)*4 + reg
#pragma unroll
  for (int i = 0; i < 4; i++) {
#pragma unroll
    for (int j = 0; j < 4; j++) {
      const int gn = bx * 128 + 64 * wc + 16 * j + lm;
#pragma unroll
      for (int vv = 0; vv < 4; vv++) {
        const int gm = by * 128 + 64 * wr + 16 * i + 4 * lg + vv;
        const float y = acc[i][j][vv];
        if (MODE == 1) {
          Out[(size_t)gm * 2048 + gn] = y * 0.1f;
        } else {
          float r = __builtin_amdgcn_rcpf(y);
          r = fminf(fmaxf(r, -1.0f), 12.0f);
          const float jf = floorf(r);
          const float d0 = fmaf(jf, y, -1.0f);
          const float i0 = fminf(fmaxf(jf, 1.0f), 10.0f);
          const float i1 = fminf(fmaxf(jf + 1.0f, 1.0f), 10.0f);
          const float e0 = fmaf(i0, y, -1.0f);
          const float e1 = fmaf(i1, y, -1.0f);
          const float mind = fminf(fabsf(e0), fabsf(e1));
          const unsigned J = (unsigned)(int)((d0 >= 0.0f) ? jf : jf + 1.0f);
          MaskJ[(size_t)gm * 6144 + gn] = (unsigned char)((J <= 10u) ? J : 0u);
          if (mind < FLAG_EPS) {
            const unsigned idx = atomicAdd(cnt, 1u);
            if (idx < LIST_CAP) list[idx] = ((unsigned)gm << 13) | (unsigned)gn;
          }
        }
      }
    }
  }
}

// ---- transpose W -> WT f32 (rescue source)
__global__ __launch_bounds__(256) void transpose_w(
    const float* __restrict__ W0, const float* __restrict__ W1,
    const float* __restrict__ W2, float* __restrict__ WT) {
  __shared__ float tile[32][33];
  const int k0 = blockIdx.x * 32;
  const int c0 = blockIdx.y * 32;
  const int sel = c0 >> 11;
  const float* W = (sel == 0) ? W0 : ((sel == 1) ? W1 : W2);
  const int cc0 = c0 & 2047;
  const int tx = threadIdx.x, ty = threadIdx.y;  // (32,8)
#pragma unroll
  for (int rep = 0; rep < 4; rep++)
    tile[ty + 8 * rep][tx] = W[(size_t)(k0 + ty + 8 * rep) * 2048 + cc0 + tx];
  __syncthreads();
#pragma unroll
  for (int rep = 0; rep < 4; rep++)
    WT[(size_t)(c0 + ty + 8 * rep) * 2048 + k0 + tx] = tile[tx][ty + 8 * rep];
}

// ---- rescue: fp64 dot for flagged channels -> first-spike J (u8)
__global__ __launch_bounds__(256) void rescue(
    const float* __restrict__ X, const float* __restrict__ WT,
    const unsigned* __restrict__ list, const unsigned* __restrict__ cnt,
    unsigned char* __restrict__ MaskJ) {
  const unsigned nItems = min(*cnt, LIST_CAP);
  const unsigned gtid = blockIdx.x * blockDim.x + threadIdx.x;
  const unsigned wave = gtid >> 6, lane = gtid & 63;
  const unsigned nWaves = (gridDim.x * blockDim.x) >> 6;

  for (unsigned i = wave; i < nItems; i += nWaves) {
    const unsigned e = list[i];
    const int r = (int)(e >> 13), c = (int)(e & 8191u);
    const float* xrow = X + (size_t)((r < 2048) ? r : r - 2048) * 2048;
    const float sg = (r < 2048) ? 1.f : -1.f;
    const float* wrow = WT + (size_t)c * 2048;
    double s = 0.0;
#pragma unroll
    for (int it = 0; it < 8; it++) {
      const int k = (it * 64 + (int)lane) * 4;
      const float4 xv = *(const float4*)(xrow + k);
      const float4 wv = *(const float4*)(wrow + k);
      const float a0 = fmaxf(sg * xv.x, 0.f);
      const float a1 = fmaxf(sg * xv.y, 0.f);
      const float a2 = fmaxf(sg * xv.z, 0.f);
      const float a3 = fmaxf(sg * xv.w, 0.f);
      s += (double)a0 * (double)wv.x + (double)a1 * (double)wv.y +
           (double)a2 * (double)wv.z + (double)a3 * (double)wv.w;
    }
#pragma unroll
    for (int off = 32; off > 0; off >>= 1) s += __shfl_down(s, off);
    if (lane == 0) {
      double v = 0.0;
      unsigned J = 0;
#pragma unroll
      for (int t = 0; t < 10; t++) {
        v += s;
        if (J == 0u && v >= 1.0) J = (unsigned)(t + 1);
      }
      MaskJ[(size_t)r * 6144 + c] = (unsigned char)J;
    }
  }
}

// ---- spike_attn: per-token attention. QK via wave-ballot bitpack + popcount
// (exact integers, bit-identical to the float dot); PV float with xv in
// conflict-free [m][d] LDS; output transpose (d,h)->d*16+h.
__global__ __launch_bounds__(256) void spike_attn(const unsigned char* __restrict__ MaskJ,
                                                  float* __restrict__ xbar) {
  const int n = blockIdx.x;
  const int tid = threadIdx.x;
  const int lane = tid & 63;

  __shared__ unsigned long long qpB[16][2], qnB[16][2], kpB[16][2], knB[16][2];
  __shared__ float xvT[16 * 132];   // [m][d], stride 132 (conflict-free)
  __shared__ float attnS[16 * 17];  // [h][m], stride 17 (conflict-free)
  __shared__ unsigned lutS[16];

  if (tid < 16) lutS[tid] = d_LUT[tid];
  __syncthreads();

  const unsigned char* mp = MaskJ + (size_t)n * 6144;
  const unsigned char* mn = MaskJ + (size_t)(n + 2048) * 6144;

  unsigned q_p[8], q_n[8], k_p[8], k_n[8], v_p[8], v_n[8];
#pragma unroll
  for (int j = 0; j < 8; j++) {
    const int c = tid + 256 * j;
    q_p[j] = lutS[mp[c]];        q_n[j] = lutS[mn[c]];
    k_p[j] = lutS[mp[2048 + c]]; k_n[j] = lutS[mn[2048 + c]];
    v_p[j] = lutS[mp[4096 + c]]; v_n[j] = lutS[mn[4096 + c]];
  }

  float acc[8];
#pragma unroll
  for (int j = 0; j < 8; j++) acc[j] = 0.f;

  for (int t = 0; t < 10; t++) {
    // ---- bitpack spikes (ballot) + xv floats
#pragma unroll
    for (int j = 0; j < 8; j++) {
      const int c = tid + 256 * j;  // wave-uniform upper bits
      const unsigned long long bqp = __ballot((q_p[j] >> t) & 1u);
      const unsigned long long bqn = __ballot((q_n[j] >> t) & 1u);
      const unsigned long long bkp = __ballot((k_p[j] >> t) & 1u);
      const unsigned long long bkn = __ballot((k_n[j] >> t) & 1u);
      const int h = c >> 7, word = (c >> 6) & 1;
      if (lane == 0) {
        qpB[h][word] = bqp; qnB[h][word] = bqn;
        kpB[h][word] = bkp; knB[h][word] = bkn;
      }
      const int m = h, d = c & 127;
      xvT[m * 132 + d] =
          (float)((v_p[j] >> t) & 1u) - (float)((v_n[j] >> t) & 1u);
    }
    __syncthreads();

    // ---- attn[h][m] = 0.125 * popcount dot (exact)
    {
      const int h = tid >> 4, m = tid & 15;
      int dot = 0;
#pragma unroll
      for (int w = 0; w < 2; w++) {
        const unsigned long long qp = qpB[h][w], qn = qnB[h][w];
        const unsigned long long kp = kpB[m][w], kn = knB[m][w];
        dot += __popcll(qp & kp) + __popcll(qn & kn) -
               __popcll(qp & kn) - __popcll(qn & kp);
      }
      attnS[h * 17 + m] = (float)dot * 0.125f;
    }
    __syncthreads();

    // ---- PV: output o = d*16 + h; h = tid&15 constant across j
    {
      const int h = tid & 15;
      float arow[16];
#pragma unroll
      for (int m = 0; m < 16; m++) arow[m] = attnS[h * 17 + m];
#pragma unroll
      for (int j = 0; j < 8; j++) {
        const int d = (tid + 256 * j) >> 4;
        float s = 0.f;
#pragma unroll
        for (int m = 0; m < 16; m++) s += arow[m] * xvT[m * 132 + d];
        acc[j] += s;
      }
    }
    __syncthreads();
  }

#pragma unroll
  for (int j = 0; j < 8; j++) xbar[(size_t)n * 2048 + tid + 256 * j] = acc[j];
}

extern "C" void kernel_launch(void* const* d_in, const int* in_sizes, int n_in,
                              void* d_out, int out_size, void* d_ws, size_t ws_size,
                              hipStream_t stream) {
  const float* x = (const float*)d_in[0];
  // d_in[1] = freqs_cis (unused)
  const float* wq = (const float*)d_in[2];
  const float* wk = (const float*)d_in[3];
  const float* wv = (const float*)d_in[4];
  const float* wo = (const float*)d_in[5];
  float* out = (float*)d_out;

  char* ws = (char*)d_ws;
  unsigned char* MaskJ = (unsigned char*)ws;                       // 25.17 MB @0
  unsigned short* WOpk = (unsigned short*)ws;                      // 16.78 MB (MaskJ dead)
  char* reg2 = ws + (size_t)4096 * 6144;                           // @25.17 MB
  unsigned short* Bpk = (unsigned short*)reg2;                     // 50.33 MB
  float* WT = (float*)reg2;                                        // (Bpk dead)
  unsigned short* Xbpk = (unsigned short*)reg2;                    // 16.78 MB (WT dead)
  char* reg3 = reg2 + (size_t)6144 * 2048 * 2 * 2;                 // @75.50 MB
  unsigned short* Apk = (unsigned short*)reg3;                     // 33.55 MB
  float* xbar = (float*)reg3;                                      // 16.78 MB (Apk dead)
  unsigned* list = (unsigned*)(reg3 + (size_t)4096 * 2048 * 2 * 2);  // 2 MB @109.05
  unsigned* cnt = list + LIST_CAP;

  wsplit<1><<<dim3(48, 64), 256, 0, stream>>>(wq, wk, wv, Bpk, 48, cnt);
  asplit<1><<<dim3(32, 64), 256, 0, stream>>>(x, Apk, 32);
  gemm_dma<0><<<dim3(48, 32), 256, 0, stream>>>(Apk, Bpk, 32, 48, MaskJ, list, cnt, nullptr);
  transpose_w<<<dim3(64, 192), dim3(32, 8), 0, stream>>>(wq, wk, wv, WT);
  rescue<<<2048, 256, 0, stream>>>(x, WT, list, cnt, MaskJ);
  spike_attn<<<2048, 256, 0, stream>>>(MaskJ, xbar);
  wsplit<0><<<dim3(16, 64), 256, 0, stream>>>(wo, wo, wo, WOpk, 16, nullptr);
  asplit<0><<<dim3(16, 64), 256, 0, stream>>>(xbar, Xbpk, 16);
  gemm_dma<1><<<dim3(16, 16), 256, 0, stream>>>(Xbpk, WOpk, 16, 16, nullptr, nullptr, nullptr, out);
}